// Round 4
// baseline (551.544 us; speedup 1.0000x reference)
//
#include <hip/hip_runtime.h>

#define DEVI __device__ __forceinline__

typedef short bf16x8 __attribute__((ext_vector_type(8)));
typedef float f32x4 __attribute__((ext_vector_type(4)));

constexpr int Bb = 8, TX = 1024, TC = 2048, CC = 512, NH = 8, HD = 64;

// fp32 -> bf16 round-to-nearest-even (values here are well-behaved, no NaN/Inf)
DEVI unsigned short f2bf(float f) {
  union { float f; unsigned u; } v; v.f = f;
  return (unsigned short)((v.u + 0x7FFFu + ((v.u >> 16) & 1u)) >> 16);
}

DEVI f32x4 mfma16(bf16x8 a, bf16x8 b, f32x4 c) {
  return __builtin_amdgcn_mfma_f32_16x16x32_bf16(a, b, c, 0, 0, 0);
}

DEVI f32x4 zero4() { f32x4 z = {0.f, 0.f, 0.f, 0.f}; return z; }

// ---------------------------------------------------------------------------
// NT GEMM: out[r][c] = sum_k A[r][k] * W[c][k] + bias[c]
// A: (M x 512) fp32 row-major.  W: (512 x 512) fp32 row-major (= B^T).
// MODE 0: out bf16 permuted to (b, h, t, d).   MODE 1: out fp32 (r*512+c).
// MODE 2: out bf16 permuted to (b, h, d, t)  [transposed — for V].
// 64x64 tile, BK=32, 256 threads = 4 waves in 2x2, each wave 32x32 (2x2 MFMA frags).
// ---------------------------------------------------------------------------
template <int MODE>
__global__ __launch_bounds__(256) void proj_gemm(
    const float* __restrict__ A, const float* __restrict__ W,
    const float* __restrict__ bias, void* __restrict__ outp, int tlog2) {
  // stride 40 shorts (=80B): keeps b128 reads 16B-aligned, spreads rows over banks
  // (k only spans 0..31 here, so stride 40 > 32 is safe)
  __shared__ __align__(16) unsigned short As[64 * 40];
  __shared__ __align__(16) unsigned short Bs[64 * 40];

  const int tid = threadIdx.x;
  const int wid = tid >> 6, l = tid & 63, l15 = l & 15, lhi = l >> 4;
  const int wm = wid >> 1, wn = wid & 1;
  const int mbase = blockIdx.y * 64, nbase = blockIdx.x * 64;
  const int sr = tid >> 2, sc0 = (tid & 3) * 8;

  f32x4 acc[2][2];
#pragma unroll
  for (int i = 0; i < 2; i++)
#pragma unroll
    for (int j = 0; j < 2; j++) acc[i][j] = zero4();

  for (int k0 = 0; k0 < CC; k0 += 32) {
    {
      const float* ap = A + (size_t)(mbase + sr) * CC + k0 + sc0;
      f32x4 f0 = *(const f32x4*)ap;
      f32x4 f1 = *(const f32x4*)(ap + 4);
      bf16x8 va;
#pragma unroll
      for (int i = 0; i < 4; i++) {
        va[i] = (short)f2bf(f0[i]);
        va[i + 4] = (short)f2bf(f1[i]);
      }
      *(bf16x8*)&As[sr * 40 + sc0] = va;

      const float* bp = W + (size_t)(nbase + sr) * CC + k0 + sc0;
      f32x4 g0 = *(const f32x4*)bp;
      f32x4 g1 = *(const f32x4*)(bp + 4);
      bf16x8 vb;
#pragma unroll
      for (int i = 0; i < 4; i++) {
        vb[i] = (short)f2bf(g0[i]);
        vb[i + 4] = (short)f2bf(g1[i]);
      }
      *(bf16x8*)&Bs[sr * 40 + sc0] = vb;
    }
    __syncthreads();

    bf16x8 a0 = *(const bf16x8*)&As[(wm * 32 + l15) * 40 + lhi * 8];
    bf16x8 a1 = *(const bf16x8*)&As[(wm * 32 + 16 + l15) * 40 + lhi * 8];
    bf16x8 b0 = *(const bf16x8*)&Bs[(wn * 32 + l15) * 40 + lhi * 8];
    bf16x8 b1 = *(const bf16x8*)&Bs[(wn * 32 + 16 + l15) * 40 + lhi * 8];
    acc[0][0] = mfma16(a0, b0, acc[0][0]);
    acc[0][1] = mfma16(a0, b1, acc[0][1]);
    acc[1][0] = mfma16(a1, b0, acc[1][0]);
    acc[1][1] = mfma16(a1, b1, acc[1][1]);
    __syncthreads();
  }

#pragma unroll
  for (int mi = 0; mi < 2; mi++)
#pragma unroll
    for (int ni = 0; ni < 2; ni++)
#pragma unroll
      for (int r = 0; r < 4; r++) {
        int grow = mbase + wm * 32 + mi * 16 + 4 * lhi + r;
        int gcol = nbase + wn * 32 + ni * 16 + l15;
        float val = acc[mi][ni][r] + bias[gcol];
        if (MODE == 0) {
          int T = 1 << tlog2;
          int bq = grow >> tlog2, tt = grow & (T - 1);
          int h = gcol >> 6, d = gcol & 63;
          size_t oidx = ((size_t)(bq * NH + h) * T + tt) * HD + d;
          ((unsigned short*)outp)[oidx] = f2bf(val);
        } else if (MODE == 2) {
          int T = 1 << tlog2;
          int bq = grow >> tlog2, tt = grow & (T - 1);
          int h = gcol >> 6, d = gcol & 63;
          size_t oidx = ((size_t)(bq * NH + h) * HD + d) * T + tt;  // V^T: (b,h,d,t)
          ((unsigned short*)outp)[oidx] = f2bf(val);
        } else {
          ((float*)outp)[(size_t)grow * CC + gcol] = val;
        }
      }
}

// ---------------------------------------------------------------------------
// Flash attention fwd v2. Block = 4 waves, each wave owns a 16-row q-tile of
// the same (b,h). Barrier-free main loop: K and V^T fragments are read
// directly from global (L1/L2-hot, 16 rows x 64B coalesced per instr); the
// only LDS is the per-wave P transpose tile (same-wave ds ordering, no
// __syncthreads needed). Defer-max (T13): rescale only when the tile max
// exceeds the running max by >5 (p bounded by e^5; p/l shift-invariant so
// att_mean stays exact).
// Writes y_pre (fp32, (b,t,c)) and per-row running max m / inverse-sum 1/l.
// ---------------------------------------------------------------------------
__global__ __launch_bounds__(256) void attn_fwd(
    const unsigned short* __restrict__ Qw, const unsigned short* __restrict__ Kw,
    const unsigned short* __restrict__ Vtw, float* __restrict__ y_pre,
    float* __restrict__ m_ws, float* __restrict__ il_ws) {
  __shared__ __align__(16) unsigned short plds[4][16 * 72];  // per-wave P tiles [row][key]

  const int tid = threadIdx.x;
  const int wid = tid >> 6, l = tid & 63, l15 = l & 15, lhi = l >> 4;
  const int qg = blockIdx.x, h = blockIdx.y, b = blockIdx.z;
  const int qbase = qg * 64 + wid * 16;

  const unsigned short* Qh = Qw + (size_t)(b * NH + h) * TX * HD;
  const unsigned short* Kh = Kw + (size_t)(b * NH + h) * TC * HD;
  const unsigned short* Vt = Vtw + (size_t)(b * NH + h) * TC * HD;  // (d, t) layout

  // Q A-frags (constant over the whole K loop): row=l15, k=8*lhi+e (+32 second half)
  bf16x8 aq0 = *(const bf16x8*)(Qh + (size_t)(qbase + l15) * HD + lhi * 8);
  bf16x8 aq1 = *(const bf16x8*)(Qh + (size_t)(qbase + l15) * HD + 32 + lhi * 8);

  f32x4 accy[4];
#pragma unroll
  for (int db = 0; db < 4; db++) accy[db] = zero4();
  float mrun[4], lrun[4];
#pragma unroll
  for (int r = 0; r < 4; r++) { mrun[r] = -1e30f; lrun[r] = 0.f; }

  unsigned short* pw = &plds[wid][0];

  for (int kt = 0; kt < TC / 64; kt++) {
    const int keyb = kt * 64;

    // issue all 16 global b128 loads first (independent -> deep MLP)
    bf16x8 bk0[4], bk1[4], bv0[4], bv1[4];
#pragma unroll
    for (int kb = 0; kb < 4; kb++) {
      const unsigned short* kp = Kh + (size_t)(keyb + kb * 16 + l15) * HD + lhi * 8;
      bk0[kb] = *(const bf16x8*)kp;
      bk1[kb] = *(const bf16x8*)(kp + 32);
    }
#pragma unroll
    for (int db = 0; db < 4; db++) {
      const unsigned short* vp = Vt + (size_t)(db * 16 + l15) * TC + keyb + lhi * 8;
      bv0[db] = *(const bf16x8*)vp;
      bv1[db] = *(const bf16x8*)(vp + 32);
    }

    // QK^T for 4 key-blocks of 16
    f32x4 s[4];
#pragma unroll
    for (int kb = 0; kb < 4; kb++) {
      f32x4 a = zero4();
      a = mfma16(aq0, bk0[kb], a);
      a = mfma16(aq1, bk1[kb], a);
      s[kb] = a * 0.125f;  // 1/sqrt(64)
    }

    // per-row tile max (rows r live on the 16 lanes of each lhi group)
    float pm[4];
#pragma unroll
    for (int r = 0; r < 4; r++) {
      float mx = fmaxf(fmaxf(s[0][r], s[1][r]), fmaxf(s[2][r], s[3][r]));
#pragma unroll
      for (int off = 1; off < 16; off <<= 1) mx = fmaxf(mx, __shfl_xor(mx, off));
      pm[r] = mx;
    }
    // defer-max: only rescale when the bound would be exceeded (p <= e^5)
    float g = fmaxf(fmaxf(pm[0] - mrun[0], pm[1] - mrun[1]),
                    fmaxf(pm[2] - mrun[2], pm[3] - mrun[3]));
    if (__any(g > 5.0f)) {
#pragma unroll
      for (int r = 0; r < 4; r++) {
        float mn = fmaxf(mrun[r], pm[r]);
        float sc = __expf(mrun[r] - mn);
        lrun[r] *= sc;
        mrun[r] = mn;
#pragma unroll
        for (int db = 0; db < 4; db++) accy[db][r] *= sc;
      }
    }

    // p = exp(s - m), accumulate row sums, stage P (bf16) for the PV transpose
    float psum[4] = {0.f, 0.f, 0.f, 0.f};
#pragma unroll
    for (int kb = 0; kb < 4; kb++)
#pragma unroll
      for (int r = 0; r < 4; r++) {
        float p = __expf(s[kb][r] - mrun[r]);
        psum[r] += p;
        pw[(4 * lhi + r) * 72 + kb * 16 + l15] = f2bf(p);
      }
#pragma unroll
    for (int r = 0; r < 4; r++) {
      float ps = psum[r];
#pragma unroll
      for (int off = 1; off < 16; off <<= 1) ps += __shfl_xor(ps, off);
      lrun[r] += ps;
    }

    // PV: A = P tile (per-wave LDS transpose), B = V^T frags from global
    bf16x8 ap0 = *(const bf16x8*)&pw[l15 * 72 + lhi * 8];
    bf16x8 ap1 = *(const bf16x8*)&pw[l15 * 72 + 32 + lhi * 8];
#pragma unroll
    for (int db = 0; db < 4; db++) {
      accy[db] = mfma16(ap0, bv0[db], accy[db]);
      accy[db] = mfma16(ap1, bv1[db], accy[db]);
    }
  }

  float il[4];
#pragma unroll
  for (int r = 0; r < 4; r++) il[r] = 1.f / lrun[r];

#pragma unroll
  for (int db = 0; db < 4; db++)
#pragma unroll
    for (int r = 0; r < 4; r++) {
      int trow = qbase + 4 * lhi + r;
      y_pre[(size_t)(b * TX + trow) * CC + h * HD + db * 16 + l15] = accy[db][r] * il[r];
    }
  if (l15 == 0) {
#pragma unroll
    for (int r = 0; r < 4; r++) {
      int idx = (b * NH + h) * TX + qbase + 4 * lhi + r;
      m_ws[idx] = mrun[r];
      il_ws[idx] = il[r];
    }
  }
}

// ---------------------------------------------------------------------------
// att_mean v2: recompute QK^T per head, p = exp(s - m) * (1/l), mean over heads.
// Block: 16 q-rows x 256 keys (wave w -> 64-key slice). Head loop fully
// unrolled with double-buffered register prefetch.
// ---------------------------------------------------------------------------
__global__ __launch_bounds__(256) void att_mean_k(
    const unsigned short* __restrict__ Qw, const unsigned short* __restrict__ Kw,
    const float* __restrict__ m_ws, const float* __restrict__ il_ws,
    float* __restrict__ attm) {
  const int tid = threadIdx.x;
  const int wid = tid >> 6, l = tid & 63, l15 = l & 15, lhi = l >> 4;
  const int keyb = blockIdx.x * 256 + wid * 64;
  const int qbase = blockIdx.y * 16;
  const int b = blockIdx.z;

  const unsigned short* Qb = Qw + (size_t)b * NH * TX * HD;
  const unsigned short* Kb = Kw + (size_t)b * NH * TC * HD;

  bf16x8 aq0[2], aq1[2], bk0[2][4], bk1[2][4];
  f32x4 mm[2], ii[2];

  auto load_head = [&](int h, int p) {
    const unsigned short* qp = Qb + (size_t)h * TX * HD + (size_t)(qbase + l15) * HD + lhi * 8;
    aq0[p] = *(const bf16x8*)qp;
    aq1[p] = *(const bf16x8*)(qp + 32);
#pragma unroll
    for (int kb = 0; kb < 4; kb++) {
      const unsigned short* kp =
          Kb + (size_t)h * TC * HD + (size_t)(keyb + kb * 16 + l15) * HD + lhi * 8;
      bk0[p][kb] = *(const bf16x8*)kp;
      bk1[p][kb] = *(const bf16x8*)(kp + 32);
    }
    mm[p] = *(const f32x4*)(m_ws + (size_t)(b * NH + h) * TX + qbase + 4 * lhi);
    ii[p] = *(const f32x4*)(il_ws + (size_t)(b * NH + h) * TX + qbase + 4 * lhi);
  };

  f32x4 am[4];
#pragma unroll
  for (int kb = 0; kb < 4; kb++) am[kb] = zero4();

  load_head(0, 0);
#pragma unroll
  for (int h = 0; h < NH; h++) {
    const int p = h & 1;
    if (h + 1 < NH) load_head(h + 1, p ^ 1);  // prefetch next head
#pragma unroll
    for (int kb = 0; kb < 4; kb++) {
      f32x4 a = zero4();
      a = mfma16(aq0[p], bk0[p][kb], a);
      a = mfma16(aq1[p], bk1[p][kb], a);
#pragma unroll
      for (int r = 0; r < 4; r++)
        am[kb][r] += __expf(a[r] * 0.125f - mm[p][r]) * ii[p][r];
    }
  }

#pragma unroll
  for (int kb = 0; kb < 4; kb++)
#pragma unroll
    for (int r = 0; r < 4; r++) {
      int trow = qbase + 4 * lhi + r;
      attm[(size_t)(b * TX + trow) * TC + keyb + kb * 16 + l15] = am[kb][r] * 0.125f;
    }
}

// ---------------------------------------------------------------------------
extern "C" void kernel_launch(void* const* d_in, const int* in_sizes, int n_in,
                              void* d_out, int out_size, void* d_ws, size_t ws_size,
                              hipStream_t stream) {
  const float* x   = (const float*)d_in[0];
  const float* ctx = (const float*)d_in[1];
  const float* Wq  = (const float*)d_in[2];
  const float* bq  = (const float*)d_in[3];
  const float* Wk  = (const float*)d_in[4];
  const float* bk  = (const float*)d_in[5];
  const float* Wv  = (const float*)d_in[6];
  const float* bv  = (const float*)d_in[7];
  const float* Wo  = (const float*)d_in[8];
  const float* bo  = (const float*)d_in[9];

  float* y_out = (float*)d_out;                       // (B, Tx, C)
  float* attm  = y_out + (size_t)Bb * TX * CC;        // (B, Tx, Tc)

  // workspace layout (all 16B-aligned): ~56.5 MB
  unsigned short* q_ws = (unsigned short*)d_ws;                  // B*NH*TX*HD bf16
  unsigned short* k_ws = q_ws + (size_t)Bb * NH * TX * HD;       // B*NH*TC*HD bf16
  unsigned short* v_ws = k_ws + (size_t)Bb * NH * TC * HD;       // B*NH*TC*HD bf16 (V^T: b,h,d,t)
  float* m_ws  = (float*)(v_ws + (size_t)Bb * NH * TC * HD);     // B*NH*TX f32
  float* il_ws = m_ws + (size_t)Bb * NH * TX;                    // B*NH*TX f32
  float* y_pre = il_ws + (size_t)Bb * NH * TX;                   // B*TX*CC f32

  proj_gemm<0><<<dim3(CC / 64, (Bb * TX) / 64), 256, 0, stream>>>(x, Wq, bq, q_ws, 10);
  proj_gemm<0><<<dim3(CC / 64, (Bb * TC) / 64), 256, 0, stream>>>(ctx, Wk, bk, k_ws, 11);
  proj_gemm<2><<<dim3(CC / 64, (Bb * TC) / 64), 256, 0, stream>>>(ctx, Wv, bv, v_ws, 11);
  attn_fwd<<<dim3(TX / 64, NH, Bb), 256, 0, stream>>>(q_ws, k_ws, v_ws, y_pre, m_ws, il_ws);
  att_mean_k<<<dim3(TC / 256, TX / 16, Bb), 256, 0, stream>>>(q_ws, k_ws, m_ws, il_ws, attm);
  proj_gemm<1><<<dim3(CC / 64, (Bb * TX) / 64), 256, 0, stream>>>(y_pre, Wo, bo, y_out, 10);
}

// Round 5
// 449.789 us; speedup vs baseline: 1.2262x; 1.2262x over previous
//
#include <hip/hip_runtime.h>

#define DEVI __device__ __forceinline__

typedef short bf16x8 __attribute__((ext_vector_type(8)));
typedef float f32x4 __attribute__((ext_vector_type(4)));

constexpr int Bb = 8, TX = 1024, TC = 2048, CC = 512, NH = 8, HD = 64;

// fp32 -> bf16 round-to-nearest-even (values here are well-behaved, no NaN/Inf)
DEVI unsigned short f2bf(float f) {
  union { float f; unsigned u; } v; v.f = f;
  return (unsigned short)((v.u + 0x7FFFu + ((v.u >> 16) & 1u)) >> 16);
}

DEVI f32x4 mfma16(bf16x8 a, bf16x8 b, f32x4 c) {
  return __builtin_amdgcn_mfma_f32_16x16x32_bf16(a, b, c, 0, 0, 0);
}

DEVI f32x4 zero4() { f32x4 z = {0.f, 0.f, 0.f, 0.f}; return z; }

// ---------------------------------------------------------------------------
// Bulk fp32 -> bf16 convert (grid-stride over chunks of 8).
// ---------------------------------------------------------------------------
__global__ __launch_bounds__(256) void cvt_bf16(
    const float* __restrict__ src, unsigned short* __restrict__ dst, int n8) {
  int i = blockIdx.x * 256 + threadIdx.x;
  const int stride = gridDim.x * 256;
  for (; i < n8; i += stride) {
    f32x4 a = *(const f32x4*)(src + (size_t)i * 8);
    f32x4 b = *(const f32x4*)(src + (size_t)i * 8 + 4);
    bf16x8 v;
#pragma unroll
    for (int j = 0; j < 4; j++) {
      v[j] = (short)f2bf(a[j]);
      v[j + 4] = (short)f2bf(b[j]);
    }
    *(bf16x8*)(dst + (size_t)i * 8) = v;
  }
}

// ---------------------------------------------------------------------------
// NT GEMM, all-bf16 inputs: out[r][c] = sum_k A[r][k] * W[c][k] + bias[c]
// A: (M x 512) bf16 row-major.  W: (512 x 512) bf16 row-major (= B^T).
// MODE 0: out bf16 permuted to (b, h, t, d).   MODE 1: out fp32 (r*512+c).
// MODE 2: out bf16 permuted to (b, h, d, t)  [transposed — for V].
// 64x64 tile, BK=32, 256 threads = 4 waves in 2x2, each wave 32x32 (2x2 frags).
// Staging is a pure b128 copy (no convert VALU).
// ---------------------------------------------------------------------------
template <int MODE>
__global__ __launch_bounds__(256) void proj_gemm(
    const unsigned short* __restrict__ A, const unsigned short* __restrict__ W,
    const float* __restrict__ bias, void* __restrict__ outp, int tlog2) {
  // stride 40 shorts (=80B): keeps b128 reads 16B-aligned, spreads rows over banks
  __shared__ __align__(16) unsigned short As[64 * 40];
  __shared__ __align__(16) unsigned short Bs[64 * 40];

  const int tid = threadIdx.x;
  const int wid = tid >> 6, l = tid & 63, l15 = l & 15, lhi = l >> 4;
  const int wm = wid >> 1, wn = wid & 1;
  const int mbase = blockIdx.y * 64, nbase = blockIdx.x * 64;
  const int sr = tid >> 2, sc0 = (tid & 3) * 8;

  f32x4 acc[2][2];
#pragma unroll
  for (int i = 0; i < 2; i++)
#pragma unroll
    for (int j = 0; j < 2; j++) acc[i][j] = zero4();

  for (int k0 = 0; k0 < CC; k0 += 32) {
    *(bf16x8*)&As[sr * 40 + sc0] =
        *(const bf16x8*)(A + (size_t)(mbase + sr) * CC + k0 + sc0);
    *(bf16x8*)&Bs[sr * 40 + sc0] =
        *(const bf16x8*)(W + (size_t)(nbase + sr) * CC + k0 + sc0);
    __syncthreads();

    bf16x8 a0 = *(const bf16x8*)&As[(wm * 32 + l15) * 40 + lhi * 8];
    bf16x8 a1 = *(const bf16x8*)&As[(wm * 32 + 16 + l15) * 40 + lhi * 8];
    bf16x8 b0 = *(const bf16x8*)&Bs[(wn * 32 + l15) * 40 + lhi * 8];
    bf16x8 b1 = *(const bf16x8*)&Bs[(wn * 32 + 16 + l15) * 40 + lhi * 8];
    acc[0][0] = mfma16(a0, b0, acc[0][0]);
    acc[0][1] = mfma16(a0, b1, acc[0][1]);
    acc[1][0] = mfma16(a1, b0, acc[1][0]);
    acc[1][1] = mfma16(a1, b1, acc[1][1]);
    __syncthreads();
  }

#pragma unroll
  for (int mi = 0; mi < 2; mi++)
#pragma unroll
    for (int ni = 0; ni < 2; ni++)
#pragma unroll
      for (int r = 0; r < 4; r++) {
        int grow = mbase + wm * 32 + mi * 16 + 4 * lhi + r;
        int gcol = nbase + wn * 32 + ni * 16 + l15;
        float val = acc[mi][ni][r] + bias[gcol];
        if (MODE == 0) {
          int T = 1 << tlog2;
          int bq = grow >> tlog2, tt = grow & (T - 1);
          int h = gcol >> 6, d = gcol & 63;
          size_t oidx = ((size_t)(bq * NH + h) * T + tt) * HD + d;
          ((unsigned short*)outp)[oidx] = f2bf(val);
        } else if (MODE == 2) {
          int T = 1 << tlog2;
          int bq = grow >> tlog2, tt = grow & (T - 1);
          int h = gcol >> 6, d = gcol & 63;
          size_t oidx = ((size_t)(bq * NH + h) * HD + d) * T + tt;  // V^T: (b,h,d,t)
          ((unsigned short*)outp)[oidx] = f2bf(val);
        } else {
          ((float*)outp)[(size_t)grow * CC + gcol] = val;
        }
      }
}

// ---------------------------------------------------------------------------
// Flash attention fwd v3. Block = 4 waves sharing (b,h), each wave a 16-row
// q-tile. V^T tiles staged to LDS by straight b128 copy (no transpose VALU),
// double-buffered with ONE barrier per iteration; V prefetch issued younger
// than the K-frag loads so the QK^T wait leaves the prefetch in flight.
// Defer-max rescale (p <= e^5; p/l shift-invariant so att_mean stays exact).
// Writes y_pre (bf16, (b,t,c)) and per-row running max m / inverse-sum 1/l.
// ---------------------------------------------------------------------------
__global__ __launch_bounds__(256) void attn_fwd(
    const unsigned short* __restrict__ Qw, const unsigned short* __restrict__ Kw,
    const unsigned short* __restrict__ Vtw, unsigned short* __restrict__ y_pre,
    float* __restrict__ m_ws, float* __restrict__ il_ws) {
  __shared__ __align__(16) unsigned short vt[2][64 * 72];    // [buf][d][key]
  __shared__ __align__(16) unsigned short plds[4][16 * 72];  // per-wave P tiles

  const int tid = threadIdx.x;
  const int wid = tid >> 6, l = tid & 63, l15 = l & 15, lhi = l >> 4;
  const int qg = blockIdx.x, h = blockIdx.y, b = blockIdx.z;
  const int qbase = qg * 64 + wid * 16;

  const unsigned short* Qh = Qw + (size_t)(b * NH + h) * TX * HD;
  const unsigned short* Kh = Kw + (size_t)(b * NH + h) * TC * HD;
  const unsigned short* Vt = Vtw + (size_t)(b * NH + h) * TC * HD;  // (d, t)

  bf16x8 aq0 = *(const bf16x8*)(Qh + (size_t)(qbase + l15) * HD + lhi * 8);
  bf16x8 aq1 = *(const bf16x8*)(Qh + (size_t)(qbase + l15) * HD + 32 + lhi * 8);

  f32x4 accy[4];
#pragma unroll
  for (int db = 0; db < 4; db++) accy[db] = zero4();
  float mrun[4], lrun[4];
#pragma unroll
  for (int r = 0; r < 4; r++) { mrun[r] = -1e30f; lrun[r] = 0.f; }

  unsigned short* pw = &plds[wid][0];

  // V staging map: thread copies row d = tid>>2, cols (tid&3)*16 .. +15 (32B)
  const int vrow = tid >> 2, vcol = (tid & 3) * 16;
  const unsigned short* vsrc = Vt + (size_t)vrow * TC + vcol;

  bf16x8 vr0 = *(const bf16x8*)(vsrc);      // tile 0 prefetch
  bf16x8 vr1 = *(const bf16x8*)(vsrc + 8);

  for (int kt = 0; kt < TC / 64; kt++) {
    const int keyb = kt * 64;
    const int cur = kt & 1;

    // commit staged V tile kt to LDS (vmcnt wait only on the 2 vreg loads)
    unsigned short* vd = &vt[cur][vrow * 72 + vcol];
    *(bf16x8*)vd = vr0;
    *(bf16x8*)(vd + 8) = vr1;

    // K-frag loads for tile kt (issued before V prefetch -> QK waits vmcnt(2))
    bf16x8 bk0[4], bk1[4];
#pragma unroll
    for (int kb = 0; kb < 4; kb++) {
      const unsigned short* kp = Kh + (size_t)(keyb + kb * 16 + l15) * HD + lhi * 8;
      bk0[kb] = *(const bf16x8*)kp;
      bk1[kb] = *(const bf16x8*)(kp + 32);
    }
    // V prefetch for tile kt+1 (stays in flight across the barrier)
    if (kt + 1 < TC / 64) {
      vr0 = *(const bf16x8*)(vsrc + keyb + 64);
      vr1 = *(const bf16x8*)(vsrc + keyb + 64 + 8);
    }

    __syncthreads();  // vt[cur] writes from all waves visible

    // QK^T for 4 key-blocks of 16
    f32x4 s[4];
#pragma unroll
    for (int kb = 0; kb < 4; kb++) {
      f32x4 a = zero4();
      a = mfma16(aq0, bk0[kb], a);
      a = mfma16(aq1, bk1[kb], a);
      s[kb] = a * 0.125f;  // 1/sqrt(64)
    }

    // per-row tile max (rows r live on the 16 lanes of each lhi group)
    float pm[4];
#pragma unroll
    for (int r = 0; r < 4; r++) {
      float mx = fmaxf(fmaxf(s[0][r], s[1][r]), fmaxf(s[2][r], s[3][r]));
#pragma unroll
      for (int off = 1; off < 16; off <<= 1) mx = fmaxf(mx, __shfl_xor(mx, off));
      pm[r] = mx;
    }
    // defer-max: rescale only when the e^5 bound would be exceeded
    float g = fmaxf(fmaxf(pm[0] - mrun[0], pm[1] - mrun[1]),
                    fmaxf(pm[2] - mrun[2], pm[3] - mrun[3]));
    if (__any(g > 5.0f)) {
#pragma unroll
      for (int r = 0; r < 4; r++) {
        float mn = fmaxf(mrun[r], pm[r]);
        float sc = __expf(mrun[r] - mn);
        lrun[r] *= sc;
        mrun[r] = mn;
#pragma unroll
        for (int db = 0; db < 4; db++) accy[db][r] *= sc;
      }
    }

    // p = exp(s - m), row sums, stage P (bf16) for the PV transpose
    float psum[4] = {0.f, 0.f, 0.f, 0.f};
#pragma unroll
    for (int kb = 0; kb < 4; kb++)
#pragma unroll
      for (int r = 0; r < 4; r++) {
        float p = __expf(s[kb][r] - mrun[r]);
        psum[r] += p;
        pw[(4 * lhi + r) * 72 + kb * 16 + l15] = f2bf(p);
      }
#pragma unroll
    for (int r = 0; r < 4; r++) {
      float ps = psum[r];
#pragma unroll
      for (int off = 1; off < 16; off <<= 1) ps += __shfl_xor(ps, off);
      lrun[r] += ps;
    }

    // PV: A = P tile (per-wave LDS transpose), B = V^T tile from LDS
    bf16x8 ap0 = *(const bf16x8*)&pw[l15 * 72 + lhi * 8];
    bf16x8 ap1 = *(const bf16x8*)&pw[l15 * 72 + 32 + lhi * 8];
#pragma unroll
    for (int db = 0; db < 4; db++) {
      bf16x8 bv0 = *(const bf16x8*)&vt[cur][(db * 16 + l15) * 72 + lhi * 8];
      bf16x8 bv1 = *(const bf16x8*)&vt[cur][(db * 16 + l15) * 72 + 32 + lhi * 8];
      accy[db] = mfma16(ap0, bv0, accy[db]);
      accy[db] = mfma16(ap1, bv1, accy[db]);
    }
    // no second barrier: vt is double-buffered, plds is per-wave
  }

  float il[4];
#pragma unroll
  for (int r = 0; r < 4; r++) il[r] = 1.f / lrun[r];

#pragma unroll
  for (int db = 0; db < 4; db++)
#pragma unroll
    for (int r = 0; r < 4; r++) {
      int trow = qbase + 4 * lhi + r;
      y_pre[(size_t)(b * TX + trow) * CC + h * HD + db * 16 + l15] =
          f2bf(accy[db][r] * il[r]);
    }
  if (l15 == 0) {
#pragma unroll
    for (int r = 0; r < 4; r++) {
      int idx = (b * NH + h) * TX + qbase + 4 * lhi + r;
      m_ws[idx] = mrun[r];
      il_ws[idx] = il[r];
    }
  }
}

// ---------------------------------------------------------------------------
// att_mean: recompute QK^T per head, p = exp(s - m) * (1/l), mean over heads.
// Block: 16 q-rows x 256 keys; head loop double-buffered in registers.
// ---------------------------------------------------------------------------
__global__ __launch_bounds__(256) void att_mean_k(
    const unsigned short* __restrict__ Qw, const unsigned short* __restrict__ Kw,
    const float* __restrict__ m_ws, const float* __restrict__ il_ws,
    float* __restrict__ attm) {
  const int tid = threadIdx.x;
  const int wid = tid >> 6, l = tid & 63, l15 = l & 15, lhi = l >> 4;
  const int keyb = blockIdx.x * 256 + wid * 64;
  const int qbase = blockIdx.y * 16;
  const int b = blockIdx.z;

  const unsigned short* Qb = Qw + (size_t)b * NH * TX * HD;
  const unsigned short* Kb = Kw + (size_t)b * NH * TC * HD;

  bf16x8 aq0[2], aq1[2], bk0[2][4], bk1[2][4];
  f32x4 mm[2], ii[2];

  auto load_head = [&](int h, int p) {
    const unsigned short* qp = Qb + (size_t)h * TX * HD + (size_t)(qbase + l15) * HD + lhi * 8;
    aq0[p] = *(const bf16x8*)qp;
    aq1[p] = *(const bf16x8*)(qp + 32);
#pragma unroll
    for (int kb = 0; kb < 4; kb++) {
      const unsigned short* kp =
          Kb + (size_t)h * TC * HD + (size_t)(keyb + kb * 16 + l15) * HD + lhi * 8;
      bk0[p][kb] = *(const bf16x8*)kp;
      bk1[p][kb] = *(const bf16x8*)(kp + 32);
    }
    mm[p] = *(const f32x4*)(m_ws + (size_t)(b * NH + h) * TX + qbase + 4 * lhi);
    ii[p] = *(const f32x4*)(il_ws + (size_t)(b * NH + h) * TX + qbase + 4 * lhi);
  };

  f32x4 am[4];
#pragma unroll
  for (int kb = 0; kb < 4; kb++) am[kb] = zero4();

  load_head(0, 0);
#pragma unroll
  for (int h = 0; h < NH; h++) {
    const int p = h & 1;
    if (h + 1 < NH) load_head(h + 1, p ^ 1);  // prefetch next head
#pragma unroll
    for (int kb = 0; kb < 4; kb++) {
      f32x4 a = zero4();
      a = mfma16(aq0[p], bk0[p][kb], a);
      a = mfma16(aq1[p], bk1[p][kb], a);
#pragma unroll
      for (int r = 0; r < 4; r++)
        am[kb][r] += __expf(a[r] * 0.125f - mm[p][r]) * ii[p][r];
    }
  }

#pragma unroll
  for (int kb = 0; kb < 4; kb++)
#pragma unroll
    for (int r = 0; r < 4; r++) {
      int trow = qbase + 4 * lhi + r;
      attm[(size_t)(b * TX + trow) * TC + keyb + kb * 16 + l15] = am[kb][r] * 0.125f;
    }
}

// ---------------------------------------------------------------------------
extern "C" void kernel_launch(void* const* d_in, const int* in_sizes, int n_in,
                              void* d_out, int out_size, void* d_ws, size_t ws_size,
                              hipStream_t stream) {
  const float* x   = (const float*)d_in[0];
  const float* ctx = (const float*)d_in[1];
  const float* Wq  = (const float*)d_in[2];
  const float* bq  = (const float*)d_in[3];
  const float* Wk  = (const float*)d_in[4];
  const float* bk  = (const float*)d_in[5];
  const float* Wv  = (const float*)d_in[6];
  const float* bv  = (const float*)d_in[7];
  const float* Wo  = (const float*)d_in[8];
  const float* bo  = (const float*)d_in[9];

  float* y_out = (float*)d_out;                       // (B, Tx, C)
  float* attm  = y_out + (size_t)Bb * TX * CC;        // (B, Tx, Tc)

  // workspace layout (16B-aligned), ~53 MB total:
  unsigned short* q_ws = (unsigned short*)d_ws;                  // B*NH*TX*HD bf16
  unsigned short* k_ws = q_ws + (size_t)Bb * NH * TX * HD;       // B*NH*TC*HD bf16
  unsigned short* v_ws = k_ws + (size_t)Bb * NH * TC * HD;       // B*NH*TC*HD bf16 (V^T)
  float* m_ws  = (float*)(v_ws + (size_t)Bb * NH * TC * HD);     // B*NH*TX f32
  float* il_ws = m_ws + (size_t)Bb * NH * TX;                    // B*NH*TX f32
  unsigned short* y_pre = (unsigned short*)(il_ws + (size_t)Bb * NH * TX);  // B*TX*CC bf16
  unsigned short* wb = y_pre + (size_t)Bb * TX * CC;             // 4x CC*CC bf16
  unsigned short* wbq = wb, *wbk = wb + CC * CC, *wbv = wb + 2 * CC * CC,
                 *wbo = wb + 3 * CC * CC;

  // bf16 input overlays (consumed before their regions are overwritten):
  unsigned short* xb = k_ws;              // read by Q-GEMM, then K-GEMM overwrites
  unsigned short* cb = (unsigned short*)attm;  // read by K/V-GEMMs, att_mean_k overwrites

  const int NX8 = Bb * TX * CC / 8, NC8 = Bb * TC * CC / 8, NW8 = CC * CC / 8;
  cvt_bf16<<<dim3(2048), 256, 0, stream>>>(x, xb, NX8);
  cvt_bf16<<<dim3(2048), 256, 0, stream>>>(ctx, cb, NC8);
  cvt_bf16<<<dim3(128), 256, 0, stream>>>(Wq, wbq, NW8);
  cvt_bf16<<<dim3(128), 256, 0, stream>>>(Wk, wbk, NW8);
  cvt_bf16<<<dim3(128), 256, 0, stream>>>(Wv, wbv, NW8);
  cvt_bf16<<<dim3(128), 256, 0, stream>>>(Wo, wbo, NW8);

  proj_gemm<0><<<dim3(CC / 64, (Bb * TX) / 64), 256, 0, stream>>>(xb, wbq, bq, q_ws, 10);
  proj_gemm<0><<<dim3(CC / 64, (Bb * TC) / 64), 256, 0, stream>>>(cb, wbk, bk, k_ws, 11);
  proj_gemm<2><<<dim3(CC / 64, (Bb * TC) / 64), 256, 0, stream>>>(cb, wbv, bv, v_ws, 11);
  attn_fwd<<<dim3(TX / 64, NH, Bb), 256, 0, stream>>>(q_ws, k_ws, v_ws, y_pre, m_ws, il_ws);
  att_mean_k<<<dim3(TC / 256, TX / 16, Bb), 256, 0, stream>>>(q_ws, k_ws, m_ws, il_ws, attm);
  proj_gemm<1><<<dim3(CC / 64, (Bb * TX) / 64), 256, 0, stream>>>(y_pre, wbo, bo, y_out, 10);
}

// Round 6
// 390.447 us; speedup vs baseline: 1.4126x; 1.1520x over previous
//
#include <hip/hip_runtime.h>

#define DEVI __device__ __forceinline__

typedef short bf16x8 __attribute__((ext_vector_type(8)));
typedef float f32x4 __attribute__((ext_vector_type(4)));

constexpr int Bb = 8, TX = 1024, TC = 2048, CC = 512, NH = 8, HD = 64;

// fp32 -> bf16 round-to-nearest-even (values here are well-behaved, no NaN/Inf)
DEVI unsigned short f2bf(float f) {
  union { float f; unsigned u; } v; v.f = f;
  return (unsigned short)((v.u + 0x7FFFu + ((v.u >> 16) & 1u)) >> 16);
}

DEVI f32x4 mfma16(bf16x8 a, bf16x8 b, f32x4 c) {
  return __builtin_amdgcn_mfma_f32_16x16x32_bf16(a, b, c, 0, 0, 0);
}

DEVI f32x4 zero4() { f32x4 z = {0.f, 0.f, 0.f, 0.f}; return z; }

// ---------------------------------------------------------------------------
// Bulk fp32 -> bf16 convert (grid-stride over chunks of 8).
// ---------------------------------------------------------------------------
__global__ __launch_bounds__(256) void cvt_bf16(
    const float* __restrict__ src, unsigned short* __restrict__ dst, int n8) {
  int i = blockIdx.x * 256 + threadIdx.x;
  const int stride = gridDim.x * 256;
  for (; i < n8; i += stride) {
    f32x4 a = *(const f32x4*)(src + (size_t)i * 8);
    f32x4 b = *(const f32x4*)(src + (size_t)i * 8 + 4);
    bf16x8 v;
#pragma unroll
    for (int j = 0; j < 4; j++) {
      v[j] = (short)f2bf(a[j]);
      v[j + 4] = (short)f2bf(b[j]);
    }
    *(bf16x8*)(dst + (size_t)i * 8) = v;
  }
}

// ---------------------------------------------------------------------------
// NT GEMM, all-bf16 inputs: out[r][c] = (sum_k A[r][k]*W[c][k] + bias[c])*scale
// MODE 0: out bf16 permuted to (b, h, t, d).   MODE 1: out fp32 (r*512+c).
// MODE 2: out bf16 permuted to (b, h, d, t)  [transposed — for V].
// 64x64 tile, BK=32, 256 threads = 4 waves in 2x2, each wave 32x32 (2x2 frags).
// ---------------------------------------------------------------------------
template <int MODE>
__global__ __launch_bounds__(256) void proj_gemm(
    const unsigned short* __restrict__ A, const unsigned short* __restrict__ W,
    const float* __restrict__ bias, void* __restrict__ outp, int tlog2, float scale) {
  // stride 40 shorts (=80B): keeps b128 reads 16B-aligned, spreads rows over banks
  __shared__ __align__(16) unsigned short As[64 * 40];
  __shared__ __align__(16) unsigned short Bs[64 * 40];

  const int tid = threadIdx.x;
  const int wid = tid >> 6, l = tid & 63, l15 = l & 15, lhi = l >> 4;
  const int wm = wid >> 1, wn = wid & 1;
  const int mbase = blockIdx.y * 64, nbase = blockIdx.x * 64;
  const int sr = tid >> 2, sc0 = (tid & 3) * 8;

  f32x4 acc[2][2];
#pragma unroll
  for (int i = 0; i < 2; i++)
#pragma unroll
    for (int j = 0; j < 2; j++) acc[i][j] = zero4();

  for (int k0 = 0; k0 < CC; k0 += 32) {
    *(bf16x8*)&As[sr * 40 + sc0] =
        *(const bf16x8*)(A + (size_t)(mbase + sr) * CC + k0 + sc0);
    *(bf16x8*)&Bs[sr * 40 + sc0] =
        *(const bf16x8*)(W + (size_t)(nbase + sr) * CC + k0 + sc0);
    __syncthreads();

    bf16x8 a0 = *(const bf16x8*)&As[(wm * 32 + l15) * 40 + lhi * 8];
    bf16x8 a1 = *(const bf16x8*)&As[(wm * 32 + 16 + l15) * 40 + lhi * 8];
    bf16x8 b0 = *(const bf16x8*)&Bs[(wn * 32 + l15) * 40 + lhi * 8];
    bf16x8 b1 = *(const bf16x8*)&Bs[(wn * 32 + 16 + l15) * 40 + lhi * 8];
    acc[0][0] = mfma16(a0, b0, acc[0][0]);
    acc[0][1] = mfma16(a0, b1, acc[0][1]);
    acc[1][0] = mfma16(a1, b0, acc[1][0]);
    acc[1][1] = mfma16(a1, b1, acc[1][1]);
    __syncthreads();
  }

#pragma unroll
  for (int mi = 0; mi < 2; mi++)
#pragma unroll
    for (int ni = 0; ni < 2; ni++)
#pragma unroll
      for (int r = 0; r < 4; r++) {
        int grow = mbase + wm * 32 + mi * 16 + 4 * lhi + r;
        int gcol = nbase + wn * 32 + ni * 16 + l15;
        float val = (acc[mi][ni][r] + bias[gcol]) * scale;
        if (MODE == 0) {
          int T = 1 << tlog2;
          int bq = grow >> tlog2, tt = grow & (T - 1);
          int h = gcol >> 6, d = gcol & 63;
          size_t oidx = ((size_t)(bq * NH + h) * T + tt) * HD + d;
          ((unsigned short*)outp)[oidx] = f2bf(val);
        } else if (MODE == 2) {
          int T = 1 << tlog2;
          int bq = grow >> tlog2, tt = grow & (T - 1);
          int h = gcol >> 6, d = gcol & 63;
          size_t oidx = ((size_t)(bq * NH + h) * HD + d) * T + tt;  // V^T: (b,h,d,t)
          ((unsigned short*)outp)[oidx] = f2bf(val);
        } else {
          ((float*)outp)[(size_t)grow * CC + gcol] = val;
        }
      }
}

// ---------------------------------------------------------------------------
// Flash attention fwd v4. Block = 4 waves sharing (b,h), each wave a 16-row
// q-tile. BOTH K and V^T tiles staged in LDS (straight b128 copies, double
// buffered, one barrier/iter). Prefetch for tile kt+1 is issued at the TOP of
// iteration kt and committed to LDS at the END — a full iteration of compute
// separates issue from the pre-barrier vmcnt drain, so global latency is
// hidden without inline asm. Q is pre-scaled by 1/sqrt(64) in its projection.
// Defer-max rescale (p <= e^5; p/l shift-invariant so att_mean stays exact).
// Writes y_pre (bf16, (b,t,c)) and per-row running max m / inverse-sum 1/l.
// ---------------------------------------------------------------------------
__global__ __launch_bounds__(256) void attn_fwd(
    const unsigned short* __restrict__ Qw, const unsigned short* __restrict__ Kw,
    const unsigned short* __restrict__ Vtw, unsigned short* __restrict__ y_pre,
    float* __restrict__ m_ws, float* __restrict__ il_ws) {
  __shared__ __align__(16) unsigned short ktl[2][64 * 72];   // [buf][key][d]
  __shared__ __align__(16) unsigned short vtl[2][64 * 72];   // [buf][d][key]
  __shared__ __align__(16) unsigned short plds[4][16 * 72];  // per-wave P tiles

  const int tid = threadIdx.x;
  const int wid = tid >> 6, l = tid & 63, l15 = l & 15, lhi = l >> 4;
  const int qg = blockIdx.x, h = blockIdx.y, b = blockIdx.z;
  const int qbase = qg * 64 + wid * 16;

  const unsigned short* Qh = Qw + (size_t)(b * NH + h) * TX * HD;
  const unsigned short* Kh = Kw + (size_t)(b * NH + h) * TC * HD;
  const unsigned short* Vt = Vtw + (size_t)(b * NH + h) * TC * HD;  // (d, t)

  bf16x8 aq0 = *(const bf16x8*)(Qh + (size_t)(qbase + l15) * HD + lhi * 8);
  bf16x8 aq1 = *(const bf16x8*)(Qh + (size_t)(qbase + l15) * HD + 32 + lhi * 8);

  f32x4 accy[4];
#pragma unroll
  for (int db = 0; db < 4; db++) accy[db] = zero4();
  float mrun[4], lrun[4];
#pragma unroll
  for (int r = 0; r < 4; r++) { mrun[r] = -1e30f; lrun[r] = 0.f; }

  unsigned short* pw = &plds[wid][0];

  // staging map: thread copies rows sr and sr+32, cols sc0..sc0+7 (b128 each)
  const int sr = tid >> 3, sc0 = (tid & 7) * 8;

  // prologue: tile 0 -> regs -> LDS[0]
  bf16x8 kr0 = *(const bf16x8*)(Kh + (size_t)sr * HD + sc0);
  bf16x8 kr1 = *(const bf16x8*)(Kh + (size_t)(sr + 32) * HD + sc0);
  bf16x8 vp0 = *(const bf16x8*)(Vt + (size_t)sr * TC + sc0);
  bf16x8 vp1 = *(const bf16x8*)(Vt + (size_t)(sr + 32) * TC + sc0);
  *(bf16x8*)&ktl[0][sr * 72 + sc0] = kr0;
  *(bf16x8*)&ktl[0][(sr + 32) * 72 + sc0] = kr1;
  *(bf16x8*)&vtl[0][sr * 72 + sc0] = vp0;
  *(bf16x8*)&vtl[0][(sr + 32) * 72 + sc0] = vp1;
  __syncthreads();

  constexpr int NT = TC / 64;
  for (int kt = 0; kt < NT; kt++) {
    const int cur = kt & 1;

    // 1. issue prefetch for tile kt+1 (oldest ops of the iteration)
    if (kt + 1 < NT) {
      const int keyn = (kt + 1) * 64;
      kr0 = *(const bf16x8*)(Kh + (size_t)(keyn + sr) * HD + sc0);
      kr1 = *(const bf16x8*)(Kh + (size_t)(keyn + sr + 32) * HD + sc0);
      vp0 = *(const bf16x8*)(Vt + (size_t)sr * TC + keyn + sc0);
      vp1 = *(const bf16x8*)(Vt + (size_t)(sr + 32) * TC + keyn + sc0);
    }

    // 2. QK^T from LDS K tile (Q pre-scaled by 1/8)
    f32x4 s[4];
#pragma unroll
    for (int kb = 0; kb < 4; kb++) {
      bf16x8 bk0 = *(const bf16x8*)&ktl[cur][(kb * 16 + l15) * 72 + lhi * 8];
      bf16x8 bk1 = *(const bf16x8*)&ktl[cur][(kb * 16 + l15) * 72 + 32 + lhi * 8];
      f32x4 a = zero4();
      a = mfma16(aq0, bk0, a);
      a = mfma16(aq1, bk1, a);
      s[kb] = a;
    }

    // 3. per-row tile max (rows r live on the 16 lanes of each lhi group)
    float pm[4];
#pragma unroll
    for (int r = 0; r < 4; r++) {
      float mx = fmaxf(fmaxf(s[0][r], s[1][r]), fmaxf(s[2][r], s[3][r]));
#pragma unroll
      for (int off = 1; off < 16; off <<= 1) mx = fmaxf(mx, __shfl_xor(mx, off));
      pm[r] = mx;
    }
    // defer-max: rescale only when the e^5 bound would be exceeded
    float g = fmaxf(fmaxf(pm[0] - mrun[0], pm[1] - mrun[1]),
                    fmaxf(pm[2] - mrun[2], pm[3] - mrun[3]));
    if (__any(g > 5.0f)) {
#pragma unroll
      for (int r = 0; r < 4; r++) {
        float mn = fmaxf(mrun[r], pm[r]);
        float sc = __expf(mrun[r] - mn);
        lrun[r] *= sc;
        mrun[r] = mn;
#pragma unroll
        for (int db = 0; db < 4; db++) accy[db][r] *= sc;
      }
    }

    // 4. p = exp(s - m), row sums, stage P (bf16) for the PV transpose
    float psum[4] = {0.f, 0.f, 0.f, 0.f};
#pragma unroll
    for (int kb = 0; kb < 4; kb++)
#pragma unroll
      for (int r = 0; r < 4; r++) {
        float p = __expf(s[kb][r] - mrun[r]);
        psum[r] += p;
        pw[(4 * lhi + r) * 72 + kb * 16 + l15] = f2bf(p);
      }
#pragma unroll
    for (int r = 0; r < 4; r++) {
      float ps = psum[r];
#pragma unroll
      for (int off = 1; off < 16; off <<= 1) ps += __shfl_xor(ps, off);
      lrun[r] += ps;
    }

    // 5. PV: A = P tile (per-wave LDS transpose), B = V^T tile from LDS
    bf16x8 ap0 = *(const bf16x8*)&pw[l15 * 72 + lhi * 8];
    bf16x8 ap1 = *(const bf16x8*)&pw[l15 * 72 + 32 + lhi * 8];
#pragma unroll
    for (int db = 0; db < 4; db++) {
      bf16x8 bv0 = *(const bf16x8*)&vtl[cur][(db * 16 + l15) * 72 + lhi * 8];
      bf16x8 bv1 = *(const bf16x8*)&vtl[cur][(db * 16 + l15) * 72 + 32 + lhi * 8];
      accy[db] = mfma16(ap0, bv0, accy[db]);
      accy[db] = mfma16(ap1, bv1, accy[db]);
    }

    // 6. commit prefetch to the other buffer (loads are ~1 iteration old)
    if (kt + 1 < NT) {
      const int nxt = cur ^ 1;
      *(bf16x8*)&ktl[nxt][sr * 72 + sc0] = kr0;
      *(bf16x8*)&ktl[nxt][(sr + 32) * 72 + sc0] = kr1;
      *(bf16x8*)&vtl[nxt][sr * 72 + sc0] = vp0;
      *(bf16x8*)&vtl[nxt][(sr + 32) * 72 + sc0] = vp1;
    }
    __syncthreads();
  }

  float il[4];
#pragma unroll
  for (int r = 0; r < 4; r++) il[r] = 1.f / lrun[r];

#pragma unroll
  for (int db = 0; db < 4; db++)
#pragma unroll
    for (int r = 0; r < 4; r++) {
      int trow = qbase + 4 * lhi + r;
      y_pre[(size_t)(b * TX + trow) * CC + h * HD + db * 16 + l15] =
          f2bf(accy[db][r] * il[r]);
    }
  if (l15 == 0) {
#pragma unroll
    for (int r = 0; r < 4; r++) {
      int idx = (b * NH + h) * TX + qbase + 4 * lhi + r;
      m_ws[idx] = mrun[r];
      il_ws[idx] = il[r];
    }
  }
}

// ---------------------------------------------------------------------------
// att_mean: recompute QK^T per head (Q pre-scaled), p = exp(s-m)*(1/l),
// mean over heads. Block: 16 q-rows x 256 keys; head loop double-buffered.
// ---------------------------------------------------------------------------
__global__ __launch_bounds__(256) void att_mean_k(
    const unsigned short* __restrict__ Qw, const unsigned short* __restrict__ Kw,
    const float* __restrict__ m_ws, const float* __restrict__ il_ws,
    float* __restrict__ attm) {
  const int tid = threadIdx.x;
  const int wid = tid >> 6, l = tid & 63, l15 = l & 15, lhi = l >> 4;
  const int keyb = blockIdx.x * 256 + wid * 64;
  const int qbase = blockIdx.y * 16;
  const int b = blockIdx.z;

  const unsigned short* Qb = Qw + (size_t)b * NH * TX * HD;
  const unsigned short* Kb = Kw + (size_t)b * NH * TC * HD;

  bf16x8 aq0[2], aq1[2], bk0[2][4], bk1[2][4];
  f32x4 mm[2], ii[2];

  auto load_head = [&](int h, int p) {
    const unsigned short* qp = Qb + (size_t)h * TX * HD + (size_t)(qbase + l15) * HD + lhi * 8;
    aq0[p] = *(const bf16x8*)qp;
    aq1[p] = *(const bf16x8*)(qp + 32);
#pragma unroll
    for (int kb = 0; kb < 4; kb++) {
      const unsigned short* kp =
          Kb + (size_t)h * TC * HD + (size_t)(keyb + kb * 16 + l15) * HD + lhi * 8;
      bk0[p][kb] = *(const bf16x8*)kp;
      bk1[p][kb] = *(const bf16x8*)(kp + 32);
    }
    mm[p] = *(const f32x4*)(m_ws + (size_t)(b * NH + h) * TX + qbase + 4 * lhi);
    ii[p] = *(const f32x4*)(il_ws + (size_t)(b * NH + h) * TX + qbase + 4 * lhi);
  };

  f32x4 am[4];
#pragma unroll
  for (int kb = 0; kb < 4; kb++) am[kb] = zero4();

  load_head(0, 0);
#pragma unroll
  for (int h = 0; h < NH; h++) {
    const int p = h & 1;
    if (h + 1 < NH) load_head(h + 1, p ^ 1);  // prefetch next head
#pragma unroll
    for (int kb = 0; kb < 4; kb++) {
      f32x4 a = zero4();
      a = mfma16(aq0[p], bk0[p][kb], a);
      a = mfma16(aq1[p], bk1[p][kb], a);
#pragma unroll
      for (int r = 0; r < 4; r++)
        am[kb][r] += __expf(a[r] - mm[p][r]) * ii[p][r];
    }
  }

#pragma unroll
  for (int kb = 0; kb < 4; kb++)
#pragma unroll
    for (int r = 0; r < 4; r++) {
      int trow = qbase + 4 * lhi + r;
      attm[(size_t)(b * TX + trow) * TC + keyb + kb * 16 + l15] = am[kb][r] * 0.125f;
    }
}

// ---------------------------------------------------------------------------
extern "C" void kernel_launch(void* const* d_in, const int* in_sizes, int n_in,
                              void* d_out, int out_size, void* d_ws, size_t ws_size,
                              hipStream_t stream) {
  const float* x   = (const float*)d_in[0];
  const float* ctx = (const float*)d_in[1];
  const float* Wq  = (const float*)d_in[2];
  const float* bq  = (const float*)d_in[3];
  const float* Wk  = (const float*)d_in[4];
  const float* bk  = (const float*)d_in[5];
  const float* Wv  = (const float*)d_in[6];
  const float* bv  = (const float*)d_in[7];
  const float* Wo  = (const float*)d_in[8];
  const float* bo  = (const float*)d_in[9];

  float* y_out = (float*)d_out;                       // (B, Tx, C)
  float* attm  = y_out + (size_t)Bb * TX * CC;        // (B, Tx, Tc)

  // workspace layout (16B-aligned), ~53 MB total:
  unsigned short* q_ws = (unsigned short*)d_ws;                  // B*NH*TX*HD bf16
  unsigned short* k_ws = q_ws + (size_t)Bb * NH * TX * HD;       // B*NH*TC*HD bf16
  unsigned short* v_ws = k_ws + (size_t)Bb * NH * TC * HD;       // B*NH*TC*HD bf16 (V^T)
  float* m_ws  = (float*)(v_ws + (size_t)Bb * NH * TC * HD);     // B*NH*TX f32
  float* il_ws = m_ws + (size_t)Bb * NH * TX;                    // B*NH*TX f32
  unsigned short* y_pre = (unsigned short*)(il_ws + (size_t)Bb * NH * TX);  // B*TX*CC bf16
  unsigned short* wb = y_pre + (size_t)Bb * TX * CC;             // 4x CC*CC bf16
  unsigned short* wbq = wb, *wbk = wb + CC * CC, *wbv = wb + 2 * CC * CC,
                 *wbo = wb + 3 * CC * CC;

  // bf16 input overlays (consumed before their regions are overwritten):
  unsigned short* xb = k_ws;              // read by Q-GEMM, then K-GEMM overwrites
  unsigned short* cb = (unsigned short*)attm;  // read by K/V-GEMMs, att_mean_k overwrites

  const int NX8 = Bb * TX * CC / 8, NC8 = Bb * TC * CC / 8, NW8 = CC * CC / 8;
  cvt_bf16<<<dim3(2048), 256, 0, stream>>>(x, xb, NX8);
  cvt_bf16<<<dim3(2048), 256, 0, stream>>>(ctx, cb, NC8);
  cvt_bf16<<<dim3(128), 256, 0, stream>>>(Wq, wbq, NW8);
  cvt_bf16<<<dim3(128), 256, 0, stream>>>(Wk, wbk, NW8);
  cvt_bf16<<<dim3(128), 256, 0, stream>>>(Wv, wbv, NW8);
  cvt_bf16<<<dim3(128), 256, 0, stream>>>(Wo, wbo, NW8);

  proj_gemm<0><<<dim3(CC / 64, (Bb * TX) / 64), 256, 0, stream>>>(xb, wbq, bq, q_ws, 10, 0.125f);
  proj_gemm<0><<<dim3(CC / 64, (Bb * TC) / 64), 256, 0, stream>>>(cb, wbk, bk, k_ws, 11, 1.0f);
  proj_gemm<2><<<dim3(CC / 64, (Bb * TC) / 64), 256, 0, stream>>>(cb, wbv, bv, v_ws, 11, 1.0f);
  attn_fwd<<<dim3(TX / 64, NH, Bb), 256, 0, stream>>>(q_ws, k_ws, v_ws, y_pre, m_ws, il_ws);
  att_mean_k<<<dim3(TC / 256, TX / 16, Bb), 256, 0, stream>>>(q_ws, k_ws, m_ws, il_ws, attm);
  proj_gemm<1><<<dim3(CC / 64, (Bb * TX) / 64), 256, 0, stream>>>(y_pre, wbo, bo, y_out, 10, 1.0f);
}

// Round 7
// 390.048 us; speedup vs baseline: 1.4140x; 1.0010x over previous
//
#include <hip/hip_runtime.h>

#define DEVI __device__ __forceinline__

typedef short bf16x8 __attribute__((ext_vector_type(8)));
typedef float f32x4 __attribute__((ext_vector_type(4)));

constexpr int Bb = 8, TX = 1024, TC = 2048, CC = 512, NH = 8, HD = 64;

// fp32 -> bf16 round-to-nearest-even (values here are well-behaved, no NaN/Inf)
DEVI unsigned short f2bf(float f) {
  union { float f; unsigned u; } v; v.f = f;
  return (unsigned short)((v.u + 0x7FFFu + ((v.u >> 16) & 1u)) >> 16);
}

DEVI f32x4 mfma16(bf16x8 a, bf16x8 b, f32x4 c) {
  return __builtin_amdgcn_mfma_f32_16x16x32_bf16(a, b, c, 0, 0, 0);
}

DEVI f32x4 zero4() { f32x4 z = {0.f, 0.f, 0.f, 0.f}; return z; }

// ---------------------------------------------------------------------------
// Bulk fp32 -> bf16 convert (grid-stride over chunks of 8).
// ---------------------------------------------------------------------------
__global__ __launch_bounds__(256) void cvt_bf16(
    const float* __restrict__ src, unsigned short* __restrict__ dst, int n8) {
  int i = blockIdx.x * 256 + threadIdx.x;
  const int stride = gridDim.x * 256;
  for (; i < n8; i += stride) {
    f32x4 a = *(const f32x4*)(src + (size_t)i * 8);
    f32x4 b = *(const f32x4*)(src + (size_t)i * 8 + 4);
    bf16x8 v;
#pragma unroll
    for (int j = 0; j < 4; j++) {
      v[j] = (short)f2bf(a[j]);
      v[j + 4] = (short)f2bf(b[j]);
    }
    *(bf16x8*)(dst + (size_t)i * 8) = v;
  }
}

// ---------------------------------------------------------------------------
// NT GEMM, all-bf16 inputs: out[r][c] = (sum_k A[r][k]*W[c][k] + bias[c])*scale
// MODE 0: out bf16 permuted to (b, h, t, d).   MODE 1: out fp32 (r*512+c).
// MODE 2: out bf16 permuted to (b, h, d, t)  [transposed — for V].
// 64x64 tile, BK=32, 256 threads = 4 waves in 2x2, each wave 32x32 (2x2 frags).
// ---------------------------------------------------------------------------
template <int MODE>
__global__ __launch_bounds__(256) void proj_gemm(
    const unsigned short* __restrict__ A, const unsigned short* __restrict__ W,
    const float* __restrict__ bias, void* __restrict__ outp, int tlog2, float scale) {
  // stride 40 shorts (=80B): keeps b128 reads 16B-aligned, spreads rows over banks
  __shared__ __align__(16) unsigned short As[64 * 40];
  __shared__ __align__(16) unsigned short Bs[64 * 40];

  const int tid = threadIdx.x;
  const int wid = tid >> 6, l = tid & 63, l15 = l & 15, lhi = l >> 4;
  const int wm = wid >> 1, wn = wid & 1;
  const int mbase = blockIdx.y * 64, nbase = blockIdx.x * 64;
  const int sr = tid >> 2, sc0 = (tid & 3) * 8;

  f32x4 acc[2][2];
#pragma unroll
  for (int i = 0; i < 2; i++)
#pragma unroll
    for (int j = 0; j < 2; j++) acc[i][j] = zero4();

  for (int k0 = 0; k0 < CC; k0 += 32) {
    *(bf16x8*)&As[sr * 40 + sc0] =
        *(const bf16x8*)(A + (size_t)(mbase + sr) * CC + k0 + sc0);
    *(bf16x8*)&Bs[sr * 40 + sc0] =
        *(const bf16x8*)(W + (size_t)(nbase + sr) * CC + k0 + sc0);
    __syncthreads();

    bf16x8 a0 = *(const bf16x8*)&As[(wm * 32 + l15) * 40 + lhi * 8];
    bf16x8 a1 = *(const bf16x8*)&As[(wm * 32 + 16 + l15) * 40 + lhi * 8];
    bf16x8 b0 = *(const bf16x8*)&Bs[(wn * 32 + l15) * 40 + lhi * 8];
    bf16x8 b1 = *(const bf16x8*)&Bs[(wn * 32 + 16 + l15) * 40 + lhi * 8];
    acc[0][0] = mfma16(a0, b0, acc[0][0]);
    acc[0][1] = mfma16(a0, b1, acc[0][1]);
    acc[1][0] = mfma16(a1, b0, acc[1][0]);
    acc[1][1] = mfma16(a1, b1, acc[1][1]);
    __syncthreads();
  }

#pragma unroll
  for (int mi = 0; mi < 2; mi++)
#pragma unroll
    for (int ni = 0; ni < 2; ni++)
#pragma unroll
      for (int r = 0; r < 4; r++) {
        int grow = mbase + wm * 32 + mi * 16 + 4 * lhi + r;
        int gcol = nbase + wn * 32 + ni * 16 + l15;
        float val = (acc[mi][ni][r] + bias[gcol]) * scale;
        if (MODE == 0) {
          int T = 1 << tlog2;
          int bq = grow >> tlog2, tt = grow & (T - 1);
          int h = gcol >> 6, d = gcol & 63;
          size_t oidx = ((size_t)(bq * NH + h) * T + tt) * HD + d;
          ((unsigned short*)outp)[oidx] = f2bf(val);
        } else if (MODE == 2) {
          int T = 1 << tlog2;
          int bq = grow >> tlog2, tt = grow & (T - 1);
          int h = gcol >> 6, d = gcol & 63;
          size_t oidx = ((size_t)(bq * NH + h) * HD + d) * T + tt;  // V^T: (b,h,d,t)
          ((unsigned short*)outp)[oidx] = f2bf(val);
        } else {
          ((float*)outp)[(size_t)grow * CC + gcol] = val;
        }
      }
}

// ---------------------------------------------------------------------------
// Flash attention fwd v4. Block = 4 waves sharing (b,h), each wave a 16-row
// q-tile. BOTH K and V^T tiles staged in LDS (straight b128 copies, double
// buffered, one barrier/iter). Prefetch for tile kt+1 is issued at the TOP of
// iteration kt and committed to LDS at the END — a full iteration of compute
// separates issue from the pre-barrier vmcnt drain, so global latency is
// hidden without inline asm. Q is pre-scaled by 1/sqrt(64) in its projection.
// Defer-max rescale (p <= e^5; p/l shift-invariant so att_mean stays exact).
// Writes y_pre (bf16, (b,t,c)) and per-row running max m / inverse-sum 1/l.
// ---------------------------------------------------------------------------
__global__ __launch_bounds__(256) void attn_fwd(
    const unsigned short* __restrict__ Qw, const unsigned short* __restrict__ Kw,
    const unsigned short* __restrict__ Vtw, unsigned short* __restrict__ y_pre,
    float* __restrict__ m_ws, float* __restrict__ il_ws) {
  __shared__ __align__(16) unsigned short ktl[2][64 * 72];   // [buf][key][d]
  __shared__ __align__(16) unsigned short vtl[2][64 * 72];   // [buf][d][key]
  __shared__ __align__(16) unsigned short plds[4][16 * 72];  // per-wave P tiles

  const int tid = threadIdx.x;
  const int wid = tid >> 6, l = tid & 63, l15 = l & 15, lhi = l >> 4;
  const int qg = blockIdx.x, h = blockIdx.y, b = blockIdx.z;
  const int qbase = qg * 64 + wid * 16;

  const unsigned short* Qh = Qw + (size_t)(b * NH + h) * TX * HD;
  const unsigned short* Kh = Kw + (size_t)(b * NH + h) * TC * HD;
  const unsigned short* Vt = Vtw + (size_t)(b * NH + h) * TC * HD;  // (d, t)

  bf16x8 aq0 = *(const bf16x8*)(Qh + (size_t)(qbase + l15) * HD + lhi * 8);
  bf16x8 aq1 = *(const bf16x8*)(Qh + (size_t)(qbase + l15) * HD + 32 + lhi * 8);

  f32x4 accy[4];
#pragma unroll
  for (int db = 0; db < 4; db++) accy[db] = zero4();
  float mrun[4], lrun[4];
#pragma unroll
  for (int r = 0; r < 4; r++) { mrun[r] = -1e30f; lrun[r] = 0.f; }

  unsigned short* pw = &plds[wid][0];

  // staging map: thread copies rows sr and sr+32, cols sc0..sc0+7 (b128 each)
  const int sr = tid >> 3, sc0 = (tid & 7) * 8;

  // prologue: tile 0 -> regs -> LDS[0]
  bf16x8 kr0 = *(const bf16x8*)(Kh + (size_t)sr * HD + sc0);
  bf16x8 kr1 = *(const bf16x8*)(Kh + (size_t)(sr + 32) * HD + sc0);
  bf16x8 vp0 = *(const bf16x8*)(Vt + (size_t)sr * TC + sc0);
  bf16x8 vp1 = *(const bf16x8*)(Vt + (size_t)(sr + 32) * TC + sc0);
  *(bf16x8*)&ktl[0][sr * 72 + sc0] = kr0;
  *(bf16x8*)&ktl[0][(sr + 32) * 72 + sc0] = kr1;
  *(bf16x8*)&vtl[0][sr * 72 + sc0] = vp0;
  *(bf16x8*)&vtl[0][(sr + 32) * 72 + sc0] = vp1;
  __syncthreads();

  constexpr int NT = TC / 64;
  for (int kt = 0; kt < NT; kt++) {
    const int cur = kt & 1;

    // 1. issue prefetch for tile kt+1 (oldest ops of the iteration)
    if (kt + 1 < NT) {
      const int keyn = (kt + 1) * 64;
      kr0 = *(const bf16x8*)(Kh + (size_t)(keyn + sr) * HD + sc0);
      kr1 = *(const bf16x8*)(Kh + (size_t)(keyn + sr + 32) * HD + sc0);
      vp0 = *(const bf16x8*)(Vt + (size_t)sr * TC + keyn + sc0);
      vp1 = *(const bf16x8*)(Vt + (size_t)(sr + 32) * TC + keyn + sc0);
    }

    // 2. QK^T from LDS K tile (Q pre-scaled by 1/8)
    f32x4 s[4];
#pragma unroll
    for (int kb = 0; kb < 4; kb++) {
      bf16x8 bk0 = *(const bf16x8*)&ktl[cur][(kb * 16 + l15) * 72 + lhi * 8];
      bf16x8 bk1 = *(const bf16x8*)&ktl[cur][(kb * 16 + l15) * 72 + 32 + lhi * 8];
      f32x4 a = zero4();
      a = mfma16(aq0, bk0, a);
      a = mfma16(aq1, bk1, a);
      s[kb] = a;
    }

    // 3. per-row tile max (rows r live on the 16 lanes of each lhi group)
    float pm[4];
#pragma unroll
    for (int r = 0; r < 4; r++) {
      float mx = fmaxf(fmaxf(s[0][r], s[1][r]), fmaxf(s[2][r], s[3][r]));
#pragma unroll
      for (int off = 1; off < 16; off <<= 1) mx = fmaxf(mx, __shfl_xor(mx, off));
      pm[r] = mx;
    }
    // defer-max: rescale only when the e^5 bound would be exceeded
    float g = fmaxf(fmaxf(pm[0] - mrun[0], pm[1] - mrun[1]),
                    fmaxf(pm[2] - mrun[2], pm[3] - mrun[3]));
    if (__any(g > 5.0f)) {
#pragma unroll
      for (int r = 0; r < 4; r++) {
        float mn = fmaxf(mrun[r], pm[r]);
        float sc = __expf(mrun[r] - mn);
        lrun[r] *= sc;
        mrun[r] = mn;
#pragma unroll
        for (int db = 0; db < 4; db++) accy[db][r] *= sc;
      }
    }

    // 4. p = exp(s - m), row sums, stage P (bf16) for the PV transpose
    float psum[4] = {0.f, 0.f, 0.f, 0.f};
#pragma unroll
    for (int kb = 0; kb < 4; kb++)
#pragma unroll
      for (int r = 0; r < 4; r++) {
        float p = __expf(s[kb][r] - mrun[r]);
        psum[r] += p;
        pw[(4 * lhi + r) * 72 + kb * 16 + l15] = f2bf(p);
      }
#pragma unroll
    for (int r = 0; r < 4; r++) {
      float ps = psum[r];
#pragma unroll
      for (int off = 1; off < 16; off <<= 1) ps += __shfl_xor(ps, off);
      lrun[r] += ps;
    }

    // 5. PV: A = P tile (per-wave LDS transpose), B = V^T tile from LDS
    bf16x8 ap0 = *(const bf16x8*)&pw[l15 * 72 + lhi * 8];
    bf16x8 ap1 = *(const bf16x8*)&pw[l15 * 72 + 32 + lhi * 8];
#pragma unroll
    for (int db = 0; db < 4; db++) {
      bf16x8 bv0 = *(const bf16x8*)&vtl[cur][(db * 16 + l15) * 72 + lhi * 8];
      bf16x8 bv1 = *(const bf16x8*)&vtl[cur][(db * 16 + l15) * 72 + 32 + lhi * 8];
      accy[db] = mfma16(ap0, bv0, accy[db]);
      accy[db] = mfma16(ap1, bv1, accy[db]);
    }

    // 6. commit prefetch to the other buffer (loads are ~1 iteration old)
    if (kt + 1 < NT) {
      const int nxt = cur ^ 1;
      *(bf16x8*)&ktl[nxt][sr * 72 + sc0] = kr0;
      *(bf16x8*)&ktl[nxt][(sr + 32) * 72 + sc0] = kr1;
      *(bf16x8*)&vtl[nxt][sr * 72 + sc0] = vp0;
      *(bf16x8*)&vtl[nxt][(sr + 32) * 72 + sc0] = vp1;
    }
    __syncthreads();
  }

  float il[4];
#pragma unroll
  for (int r = 0; r < 4; r++) il[r] = 1.f / lrun[r];

#pragma unroll
  for (int db = 0; db < 4; db++)
#pragma unroll
    for (int r = 0; r < 4; r++) {
      int trow = qbase + 4 * lhi + r;
      y_pre[(size_t)(b * TX + trow) * CC + h * HD + db * 16 + l15] =
          f2bf(accy[db][r] * il[r]);
    }
  if (l15 == 0) {
#pragma unroll
    for (int r = 0; r < 4; r++) {
      int idx = (b * NH + h) * TX + qbase + 4 * lhi + r;
      m_ws[idx] = mrun[r];
      il_ws[idx] = il[r];
    }
  }
}

// ---------------------------------------------------------------------------
// att_mean v3: recompute QK^T per head (Q pre-scaled), p = exp(s-m)*(1/l),
// mean over heads. Block: 16 q-rows x 256 keys (wave -> 64-key slice).
// Head loop fully unrolled with 2-DEEP register prefetch (3 live states,
// indices h%3 compile-time after unroll): loads for head h+2 issue while
// head h computes, so issue-to-consume distance ~2 iterations covers L2
// latency. Grid x = q-tile (fastest) so consecutive blocks share the same
// K key-block -> L2/XCD locality on the dominant read stream.
// ---------------------------------------------------------------------------
__global__ __launch_bounds__(256) void att_mean_k(
    const unsigned short* __restrict__ Qw, const unsigned short* __restrict__ Kw,
    const float* __restrict__ m_ws, const float* __restrict__ il_ws,
    float* __restrict__ attm) {
  const int tid = threadIdx.x;
  const int wid = tid >> 6, l = tid & 63, l15 = l & 15, lhi = l >> 4;
  const int qbase = blockIdx.x * 16;               // x = q tile
  const int keyb = blockIdx.y * 256 + wid * 64;    // y = key block
  const int b = blockIdx.z;

  const unsigned short* Qb = Qw + (size_t)b * NH * TX * HD;
  const unsigned short* Kb = Kw + (size_t)b * NH * TC * HD;

  bf16x8 aq0[3], aq1[3], bk0[3][4], bk1[3][4];
  f32x4 mm[3], ii[3];

  auto load_head = [&](int h, int p) {
    const unsigned short* qp = Qb + (size_t)h * TX * HD + (size_t)(qbase + l15) * HD + lhi * 8;
    aq0[p] = *(const bf16x8*)qp;
    aq1[p] = *(const bf16x8*)(qp + 32);
#pragma unroll
    for (int kb = 0; kb < 4; kb++) {
      const unsigned short* kp =
          Kb + (size_t)h * TC * HD + (size_t)(keyb + kb * 16 + l15) * HD + lhi * 8;
      bk0[p][kb] = *(const bf16x8*)kp;
      bk1[p][kb] = *(const bf16x8*)(kp + 32);
    }
    mm[p] = *(const f32x4*)(m_ws + (size_t)(b * NH + h) * TX + qbase + 4 * lhi);
    ii[p] = *(const f32x4*)(il_ws + (size_t)(b * NH + h) * TX + qbase + 4 * lhi);
  };

  f32x4 am[4];
#pragma unroll
  for (int kb = 0; kb < 4; kb++) am[kb] = zero4();

  load_head(0, 0);
  load_head(1, 1);
#pragma unroll
  for (int h = 0; h < NH; h++) {
    const int p = h % 3;
    if (h + 2 < NH) load_head(h + 2, (h + 2) % 3);  // 2-deep prefetch
#pragma unroll
    for (int kb = 0; kb < 4; kb++) {
      f32x4 a = zero4();
      a = mfma16(aq0[p], bk0[p][kb], a);
      a = mfma16(aq1[p], bk1[p][kb], a);
#pragma unroll
      for (int r = 0; r < 4; r++)
        am[kb][r] += __expf(a[r] - mm[p][r]) * ii[p][r];
    }
  }

#pragma unroll
  for (int kb = 0; kb < 4; kb++)
#pragma unroll
    for (int r = 0; r < 4; r++) {
      int trow = qbase + 4 * lhi + r;
      attm[(size_t)(b * TX + trow) * TC + keyb + kb * 16 + l15] = am[kb][r] * 0.125f;
    }
}

// ---------------------------------------------------------------------------
extern "C" void kernel_launch(void* const* d_in, const int* in_sizes, int n_in,
                              void* d_out, int out_size, void* d_ws, size_t ws_size,
                              hipStream_t stream) {
  const float* x   = (const float*)d_in[0];
  const float* ctx = (const float*)d_in[1];
  const float* Wq  = (const float*)d_in[2];
  const float* bq  = (const float*)d_in[3];
  const float* Wk  = (const float*)d_in[4];
  const float* bk  = (const float*)d_in[5];
  const float* Wv  = (const float*)d_in[6];
  const float* bv  = (const float*)d_in[7];
  const float* Wo  = (const float*)d_in[8];
  const float* bo  = (const float*)d_in[9];

  float* y_out = (float*)d_out;                       // (B, Tx, C)
  float* attm  = y_out + (size_t)Bb * TX * CC;        // (B, Tx, Tc)

  // workspace layout (16B-aligned), ~53 MB total:
  unsigned short* q_ws = (unsigned short*)d_ws;                  // B*NH*TX*HD bf16
  unsigned short* k_ws = q_ws + (size_t)Bb * NH * TX * HD;       // B*NH*TC*HD bf16
  unsigned short* v_ws = k_ws + (size_t)Bb * NH * TC * HD;       // B*NH*TC*HD bf16 (V^T)
  float* m_ws  = (float*)(v_ws + (size_t)Bb * NH * TC * HD);     // B*NH*TX f32
  float* il_ws = m_ws + (size_t)Bb * NH * TX;                    // B*NH*TX f32
  unsigned short* y_pre = (unsigned short*)(il_ws + (size_t)Bb * NH * TX);  // B*TX*CC bf16
  unsigned short* wb = y_pre + (size_t)Bb * TX * CC;             // 4x CC*CC bf16
  unsigned short* wbq = wb, *wbk = wb + CC * CC, *wbv = wb + 2 * CC * CC,
                 *wbo = wb + 3 * CC * CC;

  // bf16 input overlays (consumed before their regions are overwritten):
  unsigned short* xb = k_ws;              // read by Q-GEMM, then K-GEMM overwrites
  unsigned short* cb = (unsigned short*)attm;  // read by K/V-GEMMs, att_mean_k overwrites

  const int NX8 = Bb * TX * CC / 8, NC8 = Bb * TC * CC / 8, NW8 = CC * CC / 8;
  cvt_bf16<<<dim3(2048), 256, 0, stream>>>(x, xb, NX8);
  cvt_bf16<<<dim3(2048), 256, 0, stream>>>(ctx, cb, NC8);
  cvt_bf16<<<dim3(128), 256, 0, stream>>>(Wq, wbq, NW8);
  cvt_bf16<<<dim3(128), 256, 0, stream>>>(Wk, wbk, NW8);
  cvt_bf16<<<dim3(128), 256, 0, stream>>>(Wv, wbv, NW8);
  cvt_bf16<<<dim3(128), 256, 0, stream>>>(Wo, wbo, NW8);

  proj_gemm<0><<<dim3(CC / 64, (Bb * TX) / 64), 256, 0, stream>>>(xb, wbq, bq, q_ws, 10, 0.125f);
  proj_gemm<0><<<dim3(CC / 64, (Bb * TC) / 64), 256, 0, stream>>>(cb, wbk, bk, k_ws, 11, 1.0f);
  proj_gemm<2><<<dim3(CC / 64, (Bb * TC) / 64), 256, 0, stream>>>(cb, wbv, bv, v_ws, 11, 1.0f);
  attn_fwd<<<dim3(TX / 64, NH, Bb), 256, 0, stream>>>(q_ws, k_ws, v_ws, y_pre, m_ws, il_ws);
  att_mean_k<<<dim3(TX / 16, TC / 256, Bb), 256, 0, stream>>>(q_ws, k_ws, m_ws, il_ws, attm);
  proj_gemm<1><<<dim3(CC / 64, (Bb * TX) / 64), 256, 0, stream>>>(y_pre, wbo, bo, y_out, 10, 1.0f);
}

// Round 8
// 296.410 us; speedup vs baseline: 1.8607x; 1.3159x over previous
//
#include <hip/hip_runtime.h>

#define DEVI __device__ __forceinline__

typedef short bf16x8 __attribute__((ext_vector_type(8)));
typedef float f32x4 __attribute__((ext_vector_type(4)));

constexpr int Bb = 8, TX = 1024, TC = 2048, CC = 512, NH = 8, HD = 64;

// fp32 -> bf16 round-to-nearest-even (values here are well-behaved, no NaN/Inf)
DEVI unsigned short f2bf(float f) {
  union { float f; unsigned u; } v; v.f = f;
  return (unsigned short)((v.u + 0x7FFFu + ((v.u >> 16) & 1u)) >> 16);
}

DEVI f32x4 mfma16(bf16x8 a, bf16x8 b, f32x4 c) {
  return __builtin_amdgcn_mfma_f32_16x16x32_bf16(a, b, c, 0, 0, 0);
}

DEVI f32x4 zero4() { f32x4 z = {0.f, 0.f, 0.f, 0.f}; return z; }

// ---------------------------------------------------------------------------
// Bulk fp32 -> bf16 convert (grid-stride over chunks of 8).
// ---------------------------------------------------------------------------
__global__ __launch_bounds__(256) void cvt_bf16(
    const float* __restrict__ src, unsigned short* __restrict__ dst, int n8) {
  int i = blockIdx.x * 256 + threadIdx.x;
  const int stride = gridDim.x * 256;
  for (; i < n8; i += stride) {
    f32x4 a = *(const f32x4*)(src + (size_t)i * 8);
    f32x4 b = *(const f32x4*)(src + (size_t)i * 8 + 4);
    bf16x8 v;
#pragma unroll
    for (int j = 0; j < 4; j++) {
      v[j] = (short)f2bf(a[j]);
      v[j + 4] = (short)f2bf(b[j]);
    }
    *(bf16x8*)(dst + (size_t)i * 8) = v;
  }
}

// ---------------------------------------------------------------------------
// NT GEMM, all-bf16 inputs: out[r][c] = (sum_k A[r][k]*W[c][k] + bias[c])*scale
// MODE 0: out bf16 permuted to (b, h, t, d).   MODE 1: out fp32 (r*512+c).
// MODE 2: out bf16 permuted to (b, h, d, t)  [transposed — for V].
// 64x64 tile, BK=32, 256 threads = 4 waves in 2x2, each wave 32x32 (2x2 frags).
// ---------------------------------------------------------------------------
template <int MODE>
__global__ __launch_bounds__(256) void proj_gemm(
    const unsigned short* __restrict__ A, const unsigned short* __restrict__ W,
    const float* __restrict__ bias, void* __restrict__ outp, int tlog2, float scale) {
  // stride 40 shorts (=80B): keeps b128 reads 16B-aligned, spreads rows over banks
  __shared__ __align__(16) unsigned short As[64 * 40];
  __shared__ __align__(16) unsigned short Bs[64 * 40];

  const int tid = threadIdx.x;
  const int wid = tid >> 6, l = tid & 63, l15 = l & 15, lhi = l >> 4;
  const int wm = wid >> 1, wn = wid & 1;
  const int mbase = blockIdx.y * 64, nbase = blockIdx.x * 64;
  const int sr = tid >> 2, sc0 = (tid & 3) * 8;

  f32x4 acc[2][2];
#pragma unroll
  for (int i = 0; i < 2; i++)
#pragma unroll
    for (int j = 0; j < 2; j++) acc[i][j] = zero4();

  for (int k0 = 0; k0 < CC; k0 += 32) {
    *(bf16x8*)&As[sr * 40 + sc0] =
        *(const bf16x8*)(A + (size_t)(mbase + sr) * CC + k0 + sc0);
    *(bf16x8*)&Bs[sr * 40 + sc0] =
        *(const bf16x8*)(W + (size_t)(nbase + sr) * CC + k0 + sc0);
    __syncthreads();

    bf16x8 a0 = *(const bf16x8*)&As[(wm * 32 + l15) * 40 + lhi * 8];
    bf16x8 a1 = *(const bf16x8*)&As[(wm * 32 + 16 + l15) * 40 + lhi * 8];
    bf16x8 b0 = *(const bf16x8*)&Bs[(wn * 32 + l15) * 40 + lhi * 8];
    bf16x8 b1 = *(const bf16x8*)&Bs[(wn * 32 + 16 + l15) * 40 + lhi * 8];
    acc[0][0] = mfma16(a0, b0, acc[0][0]);
    acc[0][1] = mfma16(a0, b1, acc[0][1]);
    acc[1][0] = mfma16(a1, b0, acc[1][0]);
    acc[1][1] = mfma16(a1, b1, acc[1][1]);
    __syncthreads();
  }

#pragma unroll
  for (int mi = 0; mi < 2; mi++)
#pragma unroll
    for (int ni = 0; ni < 2; ni++)
#pragma unroll
      for (int r = 0; r < 4; r++) {
        int grow = mbase + wm * 32 + mi * 16 + 4 * lhi + r;
        int gcol = nbase + wn * 32 + ni * 16 + l15;
        float val = (acc[mi][ni][r] + bias[gcol]) * scale;
        if (MODE == 0) {
          int T = 1 << tlog2;
          int bq = grow >> tlog2, tt = grow & (T - 1);
          int h = gcol >> 6, d = gcol & 63;
          size_t oidx = ((size_t)(bq * NH + h) * T + tt) * HD + d;
          ((unsigned short*)outp)[oidx] = f2bf(val);
        } else if (MODE == 2) {
          int T = 1 << tlog2;
          int bq = grow >> tlog2, tt = grow & (T - 1);
          int h = gcol >> 6, d = gcol & 63;
          size_t oidx = ((size_t)(bq * NH + h) * HD + d) * T + tt;  // V^T: (b,h,d,t)
          ((unsigned short*)outp)[oidx] = f2bf(val);
        } else {
          ((float*)outp)[(size_t)grow * CC + gcol] = val;
        }
      }
}

// ---------------------------------------------------------------------------
// Flash attention fwd v4. Block = 4 waves sharing (b,h), each wave a 16-row
// q-tile. BOTH K and V^T tiles staged in LDS (straight b128 copies, double
// buffered, one barrier/iter). Prefetch for tile kt+1 is issued at the TOP of
// iteration kt and committed to LDS at the END — the LDS commit anchors the
// loads so the compiler cannot sink them (a full iteration separates issue
// from the pre-barrier vmcnt drain). Q pre-scaled by 1/sqrt(64).
// Defer-max rescale (p <= e^5; p/l shift-invariant so att_mean stays exact).
// Writes y_pre (bf16, (b,t,c)) and per-row running max m / inverse-sum 1/l.
// ---------------------------------------------------------------------------
__global__ __launch_bounds__(256) void attn_fwd(
    const unsigned short* __restrict__ Qw, const unsigned short* __restrict__ Kw,
    const unsigned short* __restrict__ Vtw, unsigned short* __restrict__ y_pre,
    float* __restrict__ m_ws, float* __restrict__ il_ws) {
  __shared__ __align__(16) unsigned short ktl[2][64 * 72];   // [buf][key][d]
  __shared__ __align__(16) unsigned short vtl[2][64 * 72];   // [buf][d][key]
  __shared__ __align__(16) unsigned short plds[4][16 * 72];  // per-wave P tiles

  const int tid = threadIdx.x;
  const int wid = tid >> 6, l = tid & 63, l15 = l & 15, lhi = l >> 4;
  const int qg = blockIdx.x, h = blockIdx.y, b = blockIdx.z;
  const int qbase = qg * 64 + wid * 16;

  const unsigned short* Qh = Qw + (size_t)(b * NH + h) * TX * HD;
  const unsigned short* Kh = Kw + (size_t)(b * NH + h) * TC * HD;
  const unsigned short* Vt = Vtw + (size_t)(b * NH + h) * TC * HD;  // (d, t)

  bf16x8 aq0 = *(const bf16x8*)(Qh + (size_t)(qbase + l15) * HD + lhi * 8);
  bf16x8 aq1 = *(const bf16x8*)(Qh + (size_t)(qbase + l15) * HD + 32 + lhi * 8);

  f32x4 accy[4];
#pragma unroll
  for (int db = 0; db < 4; db++) accy[db] = zero4();
  float mrun[4], lrun[4];
#pragma unroll
  for (int r = 0; r < 4; r++) { mrun[r] = -1e30f; lrun[r] = 0.f; }

  unsigned short* pw = &plds[wid][0];

  // staging map: thread copies rows sr and sr+32, cols sc0..sc0+7 (b128 each)
  const int sr = tid >> 3, sc0 = (tid & 7) * 8;

  // prologue: tile 0 -> regs -> LDS[0]
  bf16x8 kr0 = *(const bf16x8*)(Kh + (size_t)sr * HD + sc0);
  bf16x8 kr1 = *(const bf16x8*)(Kh + (size_t)(sr + 32) * HD + sc0);
  bf16x8 vp0 = *(const bf16x8*)(Vt + (size_t)sr * TC + sc0);
  bf16x8 vp1 = *(const bf16x8*)(Vt + (size_t)(sr + 32) * TC + sc0);
  *(bf16x8*)&ktl[0][sr * 72 + sc0] = kr0;
  *(bf16x8*)&ktl[0][(sr + 32) * 72 + sc0] = kr1;
  *(bf16x8*)&vtl[0][sr * 72 + sc0] = vp0;
  *(bf16x8*)&vtl[0][(sr + 32) * 72 + sc0] = vp1;
  __syncthreads();

  constexpr int NT = TC / 64;
  for (int kt = 0; kt < NT; kt++) {
    const int cur = kt & 1;

    // 1. issue prefetch for tile kt+1 (oldest ops of the iteration)
    if (kt + 1 < NT) {
      const int keyn = (kt + 1) * 64;
      kr0 = *(const bf16x8*)(Kh + (size_t)(keyn + sr) * HD + sc0);
      kr1 = *(const bf16x8*)(Kh + (size_t)(keyn + sr + 32) * HD + sc0);
      vp0 = *(const bf16x8*)(Vt + (size_t)sr * TC + keyn + sc0);
      vp1 = *(const bf16x8*)(Vt + (size_t)(sr + 32) * TC + keyn + sc0);
    }

    // 2. QK^T from LDS K tile (Q pre-scaled by 1/8)
    f32x4 s[4];
#pragma unroll
    for (int kb = 0; kb < 4; kb++) {
      bf16x8 bk0 = *(const bf16x8*)&ktl[cur][(kb * 16 + l15) * 72 + lhi * 8];
      bf16x8 bk1 = *(const bf16x8*)&ktl[cur][(kb * 16 + l15) * 72 + 32 + lhi * 8];
      f32x4 a = zero4();
      a = mfma16(aq0, bk0, a);
      a = mfma16(aq1, bk1, a);
      s[kb] = a;
    }

    // 3. per-row tile max (rows r live on the 16 lanes of each lhi group)
    float pm[4];
#pragma unroll
    for (int r = 0; r < 4; r++) {
      float mx = fmaxf(fmaxf(s[0][r], s[1][r]), fmaxf(s[2][r], s[3][r]));
#pragma unroll
      for (int off = 1; off < 16; off <<= 1) mx = fmaxf(mx, __shfl_xor(mx, off));
      pm[r] = mx;
    }
    // defer-max: rescale only when the e^5 bound would be exceeded
    float g = fmaxf(fmaxf(pm[0] - mrun[0], pm[1] - mrun[1]),
                    fmaxf(pm[2] - mrun[2], pm[3] - mrun[3]));
    if (__any(g > 5.0f)) {
#pragma unroll
      for (int r = 0; r < 4; r++) {
        float mn = fmaxf(mrun[r], pm[r]);
        float sc = __expf(mrun[r] - mn);
        lrun[r] *= sc;
        mrun[r] = mn;
#pragma unroll
        for (int db = 0; db < 4; db++) accy[db][r] *= sc;
      }
    }

    // 4. p = exp(s - m), row sums, stage P (bf16) for the PV transpose
    float psum[4] = {0.f, 0.f, 0.f, 0.f};
#pragma unroll
    for (int kb = 0; kb < 4; kb++)
#pragma unroll
      for (int r = 0; r < 4; r++) {
        float p = __expf(s[kb][r] - mrun[r]);
        psum[r] += p;
        pw[(4 * lhi + r) * 72 + kb * 16 + l15] = f2bf(p);
      }
#pragma unroll
    for (int r = 0; r < 4; r++) {
      float ps = psum[r];
#pragma unroll
      for (int off = 1; off < 16; off <<= 1) ps += __shfl_xor(ps, off);
      lrun[r] += ps;
    }

    // 5. PV: A = P tile (per-wave LDS transpose), B = V^T tile from LDS
    bf16x8 ap0 = *(const bf16x8*)&pw[l15 * 72 + lhi * 8];
    bf16x8 ap1 = *(const bf16x8*)&pw[l15 * 72 + 32 + lhi * 8];
#pragma unroll
    for (int db = 0; db < 4; db++) {
      bf16x8 bv0 = *(const bf16x8*)&vtl[cur][(db * 16 + l15) * 72 + lhi * 8];
      bf16x8 bv1 = *(const bf16x8*)&vtl[cur][(db * 16 + l15) * 72 + 32 + lhi * 8];
      accy[db] = mfma16(ap0, bv0, accy[db]);
      accy[db] = mfma16(ap1, bv1, accy[db]);
    }

    // 6. commit prefetch to the other buffer (loads are ~1 iteration old)
    if (kt + 1 < NT) {
      const int nxt = cur ^ 1;
      *(bf16x8*)&ktl[nxt][sr * 72 + sc0] = kr0;
      *(bf16x8*)&ktl[nxt][(sr + 32) * 72 + sc0] = kr1;
      *(bf16x8*)&vtl[nxt][sr * 72 + sc0] = vp0;
      *(bf16x8*)&vtl[nxt][(sr + 32) * 72 + sc0] = vp1;
    }
    __syncthreads();
  }

  float il[4];
#pragma unroll
  for (int r = 0; r < 4; r++) il[r] = 1.f / lrun[r];

#pragma unroll
  for (int db = 0; db < 4; db++)
#pragma unroll
    for (int r = 0; r < 4; r++) {
      int trow = qbase + 4 * lhi + r;
      y_pre[(size_t)(b * TX + trow) * CC + h * HD + db * 16 + l15] =
          f2bf(accy[db][r] * il[r]);
    }
  if (l15 == 0) {
#pragma unroll
    for (int r = 0; r < 4; r++) {
      int idx = (b * NH + h) * TX + qbase + 4 * lhi + r;
      m_ws[idx] = mrun[r];
      il_ws[idx] = il[r];
    }
  }
}

// ---------------------------------------------------------------------------
// att_mean v4: attn_fwd-style pipeline. Block = 4 waves sharing one
// (b, 64-q-tile, 64-key-tile); loop over the 8 heads with the K tile staged
// in LDS (double-buffered, prefetch at top / commit at bottom, one barrier
// per head) — the LDS commit anchors the global loads so the compiler can't
// sink them (the R7 register-only prefetch was rescheduled away, VGPR=96
// unchanged). K staging shared by all 4 waves; consecutive blocks (x = q)
// stage the identical K tile -> L2-hot. Q/m/il double-buffered in regs.
// ---------------------------------------------------------------------------
__global__ __launch_bounds__(256) void att_mean_k(
    const unsigned short* __restrict__ Qw, const unsigned short* __restrict__ Kw,
    const float* __restrict__ m_ws, const float* __restrict__ il_ws,
    float* __restrict__ attm) {
  __shared__ __align__(16) unsigned short ktl[2][64 * 72];  // [buf][key][d]

  const int tid = threadIdx.x;
  const int wid = tid >> 6, l = tid & 63, l15 = l & 15, lhi = l >> 4;
  const int qbase = blockIdx.x * 64 + wid * 16;  // x = q tile (fastest)
  const int keyb = blockIdx.y * 64;              // y = key tile
  const int b = blockIdx.z;

  const unsigned short* Qb = Qw + (size_t)b * NH * TX * HD;
  const unsigned short* Kb = Kw + (size_t)b * NH * TC * HD;

  // staging map: thread copies K rows sr, sr+32, cols sc0..sc0+7 (b128 each)
  const int sr = tid >> 3, sc0 = (tid & 7) * 8;

  bf16x8 aq0[2], aq1[2];
  f32x4 mm[2], ii[2];

  auto load_q = [&](int h, int p) {
    const unsigned short* qp =
        Qb + ((size_t)h * TX + qbase + l15) * HD + lhi * 8;
    aq0[p] = *(const bf16x8*)qp;
    aq1[p] = *(const bf16x8*)(qp + 32);
    mm[p] = *(const f32x4*)(m_ws + (size_t)(b * NH + h) * TX + qbase + 4 * lhi);
    ii[p] = *(const f32x4*)(il_ws + (size_t)(b * NH + h) * TX + qbase + 4 * lhi);
  };

  // prologue: head 0 K tile -> regs -> LDS[0]; head-0 Q state
  bf16x8 kr0 = *(const bf16x8*)(Kb + ((size_t)keyb + sr) * HD + sc0);
  bf16x8 kr1 = *(const bf16x8*)(Kb + ((size_t)keyb + sr + 32) * HD + sc0);
  load_q(0, 0);
  *(bf16x8*)&ktl[0][sr * 72 + sc0] = kr0;
  *(bf16x8*)&ktl[0][(sr + 32) * 72 + sc0] = kr1;
  __syncthreads();

  f32x4 am[4];
#pragma unroll
  for (int kb = 0; kb < 4; kb++) am[kb] = zero4();

#pragma unroll
  for (int h = 0; h < NH; h++) {
    const int cur = h & 1;

    // 1. prefetch head h+1 (K to regs, Q/m/il to the other state)
    if (h + 1 < NH) {
      kr0 = *(const bf16x8*)(Kb + ((size_t)(h + 1) * TC + keyb + sr) * HD + sc0);
      kr1 = *(const bf16x8*)(Kb + ((size_t)(h + 1) * TC + keyb + sr + 32) * HD + sc0);
      load_q(h + 1, cur ^ 1);
    }

    // 2. QK^T from LDS K tile + exp-accumulate (Q pre-scaled by 1/8)
#pragma unroll
    for (int kb = 0; kb < 4; kb++) {
      bf16x8 bk0 = *(const bf16x8*)&ktl[cur][(kb * 16 + l15) * 72 + lhi * 8];
      bf16x8 bk1 = *(const bf16x8*)&ktl[cur][(kb * 16 + l15) * 72 + 32 + lhi * 8];
      f32x4 a = zero4();
      a = mfma16(aq0[cur], bk0, a);
      a = mfma16(aq1[cur], bk1, a);
#pragma unroll
      for (int r = 0; r < 4; r++)
        am[kb][r] += __expf(a[r] - mm[cur][r]) * ii[cur][r];
    }

    // 3. commit K prefetch (anchors the loads; ~1 head-iter old by now)
    if (h + 1 < NH) {
      const int nxt = cur ^ 1;
      *(bf16x8*)&ktl[nxt][sr * 72 + sc0] = kr0;
      *(bf16x8*)&ktl[nxt][(sr + 32) * 72 + sc0] = kr1;
    }
    __syncthreads();
  }

#pragma unroll
  for (int kb = 0; kb < 4; kb++)
#pragma unroll
    for (int r = 0; r < 4; r++) {
      int trow = qbase + 4 * lhi + r;
      attm[(size_t)(b * TX + trow) * TC + keyb + kb * 16 + l15] = am[kb][r] * 0.125f;
    }
}

// ---------------------------------------------------------------------------
extern "C" void kernel_launch(void* const* d_in, const int* in_sizes, int n_in,
                              void* d_out, int out_size, void* d_ws, size_t ws_size,
                              hipStream_t stream) {
  const float* x   = (const float*)d_in[0];
  const float* ctx = (const float*)d_in[1];
  const float* Wq  = (const float*)d_in[2];
  const float* bq  = (const float*)d_in[3];
  const float* Wk  = (const float*)d_in[4];
  const float* bk  = (const float*)d_in[5];
  const float* Wv  = (const float*)d_in[6];
  const float* bv  = (const float*)d_in[7];
  const float* Wo  = (const float*)d_in[8];
  const float* bo  = (const float*)d_in[9];

  float* y_out = (float*)d_out;                       // (B, Tx, C)
  float* attm  = y_out + (size_t)Bb * TX * CC;        // (B, Tx, Tc)

  // workspace layout (16B-aligned), ~53 MB total:
  unsigned short* q_ws = (unsigned short*)d_ws;                  // B*NH*TX*HD bf16
  unsigned short* k_ws = q_ws + (size_t)Bb * NH * TX * HD;       // B*NH*TC*HD bf16
  unsigned short* v_ws = k_ws + (size_t)Bb * NH * TC * HD;       // B*NH*TC*HD bf16 (V^T)
  float* m_ws  = (float*)(v_ws + (size_t)Bb * NH * TC * HD);     // B*NH*TX f32
  float* il_ws = m_ws + (size_t)Bb * NH * TX;                    // B*NH*TX f32
  unsigned short* y_pre = (unsigned short*)(il_ws + (size_t)Bb * NH * TX);  // B*TX*CC bf16
  unsigned short* wb = y_pre + (size_t)Bb * TX * CC;             // 4x CC*CC bf16
  unsigned short* wbq = wb, *wbk = wb + CC * CC, *wbv = wb + 2 * CC * CC,
                 *wbo = wb + 3 * CC * CC;

  // bf16 input overlays (consumed before their regions are overwritten):
  unsigned short* xb = k_ws;              // read by Q-GEMM, then K-GEMM overwrites
  unsigned short* cb = (unsigned short*)attm;  // read by K/V-GEMMs, att_mean_k overwrites

  const int NX8 = Bb * TX * CC / 8, NC8 = Bb * TC * CC / 8, NW8 = CC * CC / 8;
  cvt_bf16<<<dim3(2048), 256, 0, stream>>>(x, xb, NX8);
  cvt_bf16<<<dim3(2048), 256, 0, stream>>>(ctx, cb, NC8);
  cvt_bf16<<<dim3(128), 256, 0, stream>>>(Wq, wbq, NW8);
  cvt_bf16<<<dim3(128), 256, 0, stream>>>(Wk, wbk, NW8);
  cvt_bf16<<<dim3(128), 256, 0, stream>>>(Wv, wbv, NW8);
  cvt_bf16<<<dim3(128), 256, 0, stream>>>(Wo, wbo, NW8);

  proj_gemm<0><<<dim3(CC / 64, (Bb * TX) / 64), 256, 0, stream>>>(xb, wbq, bq, q_ws, 10, 0.125f);
  proj_gemm<0><<<dim3(CC / 64, (Bb * TC) / 64), 256, 0, stream>>>(cb, wbk, bk, k_ws, 11, 1.0f);
  proj_gemm<2><<<dim3(CC / 64, (Bb * TC) / 64), 256, 0, stream>>>(cb, wbv, bv, v_ws, 11, 1.0f);
  attn_fwd<<<dim3(TX / 64, NH, Bb), 256, 0, stream>>>(q_ws, k_ws, v_ws, y_pre, m_ws, il_ws);
  att_mean_k<<<dim3(TX / 64, TC / 64, Bb), 256, 0, stream>>>(q_ws, k_ws, m_ws, il_ws, attm);
  proj_gemm<1><<<dim3(CC / 64, (Bb * TX) / 64), 256, 0, stream>>>(y_pre, wbo, bo, y_out, 10, 1.0f);
}

// Round 9
// 264.852 us; speedup vs baseline: 2.0825x; 1.1192x over previous
//
#include <hip/hip_runtime.h>

#define DEVI __device__ __forceinline__

typedef short bf16x8 __attribute__((ext_vector_type(8)));
typedef short bf16x4 __attribute__((ext_vector_type(4)));
typedef float f32x4 __attribute__((ext_vector_type(4)));

constexpr int Bb = 8, TX = 1024, TC = 2048, CC = 512, NH = 8, HD = 64;

// fp32 -> bf16 round-to-nearest-even (values here are well-behaved, no NaN/Inf)
DEVI unsigned short f2bf(float f) {
  union { float f; unsigned u; } v; v.f = f;
  return (unsigned short)((v.u + 0x7FFFu + ((v.u >> 16) & 1u)) >> 16);
}

// packed f32x2 -> bf16x2 (low = lo, high = hi); no builtin on gfx950 (T12)
DEVI unsigned cvtpk(float lo, float hi) {
  unsigned r;
  asm("v_cvt_pk_bf16_f32 %0, %1, %2" : "=v"(r) : "v"(lo), "v"(hi));
  return r;
}

DEVI f32x4 mfma16(bf16x8 a, bf16x8 b, f32x4 c) {
  return __builtin_amdgcn_mfma_f32_16x16x32_bf16(a, b, c, 0, 0, 0);
}

DEVI f32x4 zero4() { f32x4 z = {0.f, 0.f, 0.f, 0.f}; return z; }

// ---------------------------------------------------------------------------
// Bulk fp32 -> bf16 convert (grid-stride over chunks of 8).
// ---------------------------------------------------------------------------
__global__ __launch_bounds__(256) void cvt_bf16(
    const float* __restrict__ src, unsigned short* __restrict__ dst, int n8) {
  int i = blockIdx.x * 256 + threadIdx.x;
  const int stride = gridDim.x * 256;
  for (; i < n8; i += stride) {
    f32x4 a = *(const f32x4*)(src + (size_t)i * 8);
    f32x4 b = *(const f32x4*)(src + (size_t)i * 8 + 4);
    bf16x8 v;
#pragma unroll
    for (int j = 0; j < 4; j++) {
      v[j] = (short)f2bf(a[j]);
      v[j + 4] = (short)f2bf(b[j]);
    }
    *(bf16x8*)(dst + (size_t)i * 8) = v;
  }
}

// ---------------------------------------------------------------------------
// NT GEMM, all-bf16 inputs: out[r][c] = (sum_k A[r][k]*W[c][k] + bias[c])*scale
// MODE 0: out bf16 permuted to (b, h, t, d).   MODE 1: out fp32 (r*512+c).
// MODE 2: out bf16 permuted to (b, h, d, t)  [transposed — for V].
// 64x64 tile, BK=32, 256 threads = 4 waves in 2x2, each wave 32x32 (2x2 frags).
// ---------------------------------------------------------------------------
template <int MODE>
__global__ __launch_bounds__(256) void proj_gemm(
    const unsigned short* __restrict__ A, const unsigned short* __restrict__ W,
    const float* __restrict__ bias, void* __restrict__ outp, int tlog2, float scale) {
  // stride 40 shorts (=80B): keeps b128 reads 16B-aligned, spreads rows over banks
  __shared__ __align__(16) unsigned short As[64 * 40];
  __shared__ __align__(16) unsigned short Bs[64 * 40];

  const int tid = threadIdx.x;
  const int wid = tid >> 6, l = tid & 63, l15 = l & 15, lhi = l >> 4;
  const int wm = wid >> 1, wn = wid & 1;
  const int mbase = blockIdx.y * 64, nbase = blockIdx.x * 64;
  const int sr = tid >> 2, sc0 = (tid & 3) * 8;

  f32x4 acc[2][2];
#pragma unroll
  for (int i = 0; i < 2; i++)
#pragma unroll
    for (int j = 0; j < 2; j++) acc[i][j] = zero4();

  for (int k0 = 0; k0 < CC; k0 += 32) {
    *(bf16x8*)&As[sr * 40 + sc0] =
        *(const bf16x8*)(A + (size_t)(mbase + sr) * CC + k0 + sc0);
    *(bf16x8*)&Bs[sr * 40 + sc0] =
        *(const bf16x8*)(W + (size_t)(nbase + sr) * CC + k0 + sc0);
    __syncthreads();

    bf16x8 a0 = *(const bf16x8*)&As[(wm * 32 + l15) * 40 + lhi * 8];
    bf16x8 a1 = *(const bf16x8*)&As[(wm * 32 + 16 + l15) * 40 + lhi * 8];
    bf16x8 b0 = *(const bf16x8*)&Bs[(wn * 32 + l15) * 40 + lhi * 8];
    bf16x8 b1 = *(const bf16x8*)&Bs[(wn * 32 + 16 + l15) * 40 + lhi * 8];
    acc[0][0] = mfma16(a0, b0, acc[0][0]);
    acc[0][1] = mfma16(a0, b1, acc[0][1]);
    acc[1][0] = mfma16(a1, b0, acc[1][0]);
    acc[1][1] = mfma16(a1, b1, acc[1][1]);
    __syncthreads();
  }

#pragma unroll
  for (int mi = 0; mi < 2; mi++)
#pragma unroll
    for (int ni = 0; ni < 2; ni++)
#pragma unroll
      for (int r = 0; r < 4; r++) {
        int grow = mbase + wm * 32 + mi * 16 + 4 * lhi + r;
        int gcol = nbase + wn * 32 + ni * 16 + l15;
        float val = (acc[mi][ni][r] + bias[gcol]) * scale;
        if (MODE == 0) {
          int T = 1 << tlog2;
          int bq = grow >> tlog2, tt = grow & (T - 1);
          int h = gcol >> 6, d = gcol & 63;
          size_t oidx = ((size_t)(bq * NH + h) * T + tt) * HD + d;
          ((unsigned short*)outp)[oidx] = f2bf(val);
        } else if (MODE == 2) {
          int T = 1 << tlog2;
          int bq = grow >> tlog2, tt = grow & (T - 1);
          int h = gcol >> 6, d = gcol & 63;
          size_t oidx = ((size_t)(bq * NH + h) * HD + d) * T + tt;  // V^T: (b,h,d,t)
          ((unsigned short*)outp)[oidx] = f2bf(val);
        } else {
          ((float*)outp)[(size_t)grow * CC + gcol] = val;
        }
      }
}

// ---------------------------------------------------------------------------
// Flash attention fwd v5 — swapped-QK^T in-register softmax (T12 for 16x16).
// Block = 4 waves sharing (b,h), each wave a 16-row q-tile. K and V^T staged
// in LDS (double-buffered, prefetch top / commit bottom, one barrier/iter).
// QK^T computed as mfma(K,Q) so each lane owns ONE q-row (q = l&15, keys =
// 16*kb + 4*lhi + r): softmax max/sum are in-lane chains + 2 shuffles; P goes
// to the PV B-fragment via 8 cvt_pk + 16 bpermute + 8 cndmask — NO P LDS
// tile (the old path's 16 scalar ds_writes were 4-way bank conflicted).
// PV = mfma(V,P) -> y^T layout; y stored as 4x b64. Q pre-scaled by 1/8.
// Defer-max rescale (p <= e^5; p/l shift-invariant so att_mean stays exact).
// ---------------------------------------------------------------------------
__global__ __launch_bounds__(256) void attn_fwd(
    const unsigned short* __restrict__ Qw, const unsigned short* __restrict__ Kw,
    const unsigned short* __restrict__ Vtw, unsigned short* __restrict__ y_pre,
    float* __restrict__ m_ws, float* __restrict__ il_ws) {
  __shared__ __align__(16) unsigned short ktl[2][64 * 72];  // [buf][key][d]
  __shared__ __align__(16) unsigned short vtl[2][64 * 72];  // [buf][d][key]

  const int tid = threadIdx.x;
  const int wid = tid >> 6, l = tid & 63, l15 = l & 15, lhi = l >> 4;
  const int qg = blockIdx.x, h = blockIdx.y, b = blockIdx.z;
  const int qbase = qg * 64 + wid * 16;

  const unsigned short* Qh = Qw + (size_t)(b * NH + h) * TX * HD;
  const unsigned short* Kh = Kw + (size_t)(b * NH + h) * TC * HD;
  const unsigned short* Vt = Vtw + (size_t)(b * NH + h) * TC * HD;  // (d, t)

  bf16x8 aq0 = *(const bf16x8*)(Qh + (size_t)(qbase + l15) * HD + lhi * 8);
  bf16x8 aq1 = *(const bf16x8*)(Qh + (size_t)(qbase + l15) * HD + 32 + lhi * 8);

  f32x4 accy[4];
#pragma unroll
  for (int db = 0; db < 4; db++) accy[db] = zero4();
  float mrun = -1e30f, lrun = 0.f;

  // P-redistribution lane map (derived; see round-9 notes):
  // word j of the k-octet 8*lhi comes from lane l15 + 32*(lhi&1) + 16*(j>=2),
  // pk word (j&1), kb block (lhi>>1) (+2 for the k>=32 half).
  const int sl0 = l15 + ((lhi & 1) << 5);
  const int sl1 = sl0 + 16;
  const bool sel = ((lhi >> 1) & 1) != 0;

  // staging map: thread copies rows sr and sr+32, cols sc0..sc0+7 (b128 each)
  const int sr = tid >> 3, sc0 = (tid & 7) * 8;

  // prologue: tile 0 -> regs -> LDS[0]
  bf16x8 kr0 = *(const bf16x8*)(Kh + (size_t)sr * HD + sc0);
  bf16x8 kr1 = *(const bf16x8*)(Kh + (size_t)(sr + 32) * HD + sc0);
  bf16x8 vp0 = *(const bf16x8*)(Vt + (size_t)sr * TC + sc0);
  bf16x8 vp1 = *(const bf16x8*)(Vt + (size_t)(sr + 32) * TC + sc0);
  *(bf16x8*)&ktl[0][sr * 72 + sc0] = kr0;
  *(bf16x8*)&ktl[0][(sr + 32) * 72 + sc0] = kr1;
  *(bf16x8*)&vtl[0][sr * 72 + sc0] = vp0;
  *(bf16x8*)&vtl[0][(sr + 32) * 72 + sc0] = vp1;
  __syncthreads();

  constexpr int NT = TC / 64;
  for (int kt = 0; kt < NT; kt++) {
    const int cur = kt & 1;

    // 1. issue prefetch for tile kt+1 (oldest ops of the iteration)
    if (kt + 1 < NT) {
      const int keyn = (kt + 1) * 64;
      kr0 = *(const bf16x8*)(Kh + (size_t)(keyn + sr) * HD + sc0);
      kr1 = *(const bf16x8*)(Kh + (size_t)(keyn + sr + 32) * HD + sc0);
      vp0 = *(const bf16x8*)(Vt + (size_t)sr * TC + keyn + sc0);
      vp1 = *(const bf16x8*)(Vt + (size_t)(sr + 32) * TC + keyn + sc0);
    }

    // 2. swapped QK^T: s[kb][r] = S[key=16kb+4lhi+r][q=l15]
    f32x4 s[4];
#pragma unroll
    for (int kb = 0; kb < 4; kb++) {
      bf16x8 bk0 = *(const bf16x8*)&ktl[cur][(kb * 16 + l15) * 72 + lhi * 8];
      bf16x8 bk1 = *(const bf16x8*)&ktl[cur][(kb * 16 + l15) * 72 + 32 + lhi * 8];
      f32x4 a = zero4();
      a = mfma16(bk0, aq0, a);
      a = mfma16(bk1, aq1, a);
      s[kb] = a;
    }

    // 3. per-lane softmax (this lane's q-row): in-lane max + 2 shuffles
    float mx = s[0][0];
#pragma unroll
    for (int kb = 0; kb < 4; kb++)
#pragma unroll
      for (int r = 0; r < 4; r++) mx = fmaxf(mx, s[kb][r]);
    mx = fmaxf(mx, __shfl_xor(mx, 16));
    mx = fmaxf(mx, __shfl_xor(mx, 32));

    // defer-max: rescale only when the e^5 bound would be exceeded
    if (__any(mx - mrun > 5.0f)) {
      float mn = fmaxf(mrun, mx);
      float sc = __expf(mrun - mn);
      lrun *= sc;
      mrun = mn;
#pragma unroll
      for (int db = 0; db < 4; db++)
#pragma unroll
        for (int r = 0; r < 4; r++) accy[db][r] *= sc;
    }

    // 4. p = exp(s - m); row sum in-lane + 2 shuffles
    float p[4][4];
    float ps = 0.f;
#pragma unroll
    for (int kb = 0; kb < 4; kb++)
#pragma unroll
      for (int r = 0; r < 4; r++) {
        p[kb][r] = __expf(s[kb][r] - mrun);
        ps += p[kb][r];
      }
    ps += __shfl_xor(ps, 16);
    ps += __shfl_xor(ps, 32);
    lrun += ps;

    // 5. pack P to bf16 pairs and redistribute into the PV B-fragment
    unsigned pkw[4][2];
#pragma unroll
    for (int kb = 0; kb < 4; kb++) {
      pkw[kb][0] = cvtpk(p[kb][0], p[kb][1]);
      pkw[kb][1] = cvtpk(p[kb][2], p[kb][3]);
    }
    unsigned a00 = (unsigned)__shfl((int)pkw[0][0], sl0);
    unsigned a01 = (unsigned)__shfl((int)pkw[0][1], sl0);
    unsigned a10 = (unsigned)__shfl((int)pkw[1][0], sl0);
    unsigned a11 = (unsigned)__shfl((int)pkw[1][1], sl0);
    unsigned c00 = (unsigned)__shfl((int)pkw[0][0], sl1);
    unsigned c01 = (unsigned)__shfl((int)pkw[0][1], sl1);
    unsigned c10 = (unsigned)__shfl((int)pkw[1][0], sl1);
    unsigned c11 = (unsigned)__shfl((int)pkw[1][1], sl1);
    unsigned e00 = (unsigned)__shfl((int)pkw[2][0], sl0);
    unsigned e01 = (unsigned)__shfl((int)pkw[2][1], sl0);
    unsigned e10 = (unsigned)__shfl((int)pkw[3][0], sl0);
    unsigned e11 = (unsigned)__shfl((int)pkw[3][1], sl0);
    unsigned g00 = (unsigned)__shfl((int)pkw[2][0], sl1);
    unsigned g01 = (unsigned)__shfl((int)pkw[2][1], sl1);
    unsigned g10 = (unsigned)__shfl((int)pkw[3][0], sl1);
    unsigned g11 = (unsigned)__shfl((int)pkw[3][1], sl1);
    union { unsigned u[4]; bf16x8 v; } B0, B1;
    B0.u[0] = sel ? a10 : a00;
    B0.u[1] = sel ? a11 : a01;
    B0.u[2] = sel ? c10 : c00;
    B0.u[3] = sel ? c11 : c01;
    B1.u[0] = sel ? e10 : e00;
    B1.u[1] = sel ? e11 : e01;
    B1.u[2] = sel ? g10 : g00;
    B1.u[3] = sel ? g11 : g01;

    // 6. PV swapped: accy[db][r] = y[q=l15][d=16db+4lhi+r]
#pragma unroll
    for (int db = 0; db < 4; db++) {
      bf16x8 bv0 = *(const bf16x8*)&vtl[cur][(db * 16 + l15) * 72 + lhi * 8];
      bf16x8 bv1 = *(const bf16x8*)&vtl[cur][(db * 16 + l15) * 72 + 32 + lhi * 8];
      accy[db] = mfma16(bv0, B0.v, accy[db]);
      accy[db] = mfma16(bv1, B1.v, accy[db]);
    }

    // 7. commit prefetch to the other buffer (loads are ~1 iteration old)
    if (kt + 1 < NT) {
      const int nxt = cur ^ 1;
      *(bf16x8*)&ktl[nxt][sr * 72 + sc0] = kr0;
      *(bf16x8*)&ktl[nxt][(sr + 32) * 72 + sc0] = kr1;
      *(bf16x8*)&vtl[nxt][sr * 72 + sc0] = vp0;
      *(bf16x8*)&vtl[nxt][(sr + 32) * 72 + sc0] = vp1;
    }
    __syncthreads();
  }

  const float il = 1.f / lrun;

#pragma unroll
  for (int db = 0; db < 4; db++) {
    bf16x4 o;
#pragma unroll
    for (int r = 0; r < 4; r++) o[r] = (short)f2bf(accy[db][r] * il);
    *(bf16x4*)(y_pre + (size_t)(b * TX + qbase + l15) * CC + h * HD + db * 16 +
               4 * lhi) = o;
  }
  if (lhi == 0) {
    int idx = (b * NH + h) * TX + qbase + l15;
    m_ws[idx] = mrun;
    il_ws[idx] = il;
  }
}

// ---------------------------------------------------------------------------
// att_mean v4: attn_fwd-style pipeline. Block = 4 waves sharing one
// (b, 64-q-tile, 64-key-tile); loop over the 8 heads with the K tile staged
// in LDS (double-buffered, prefetch at top / commit at bottom, one barrier
// per head) — the LDS commit anchors the global loads so the compiler can't
// sink them. K staging shared by all 4 waves; consecutive blocks (x = q)
// stage the identical K tile -> L2-hot. Q/m/il double-buffered in regs.
// ---------------------------------------------------------------------------
__global__ __launch_bounds__(256) void att_mean_k(
    const unsigned short* __restrict__ Qw, const unsigned short* __restrict__ Kw,
    const float* __restrict__ m_ws, const float* __restrict__ il_ws,
    float* __restrict__ attm) {
  __shared__ __align__(16) unsigned short ktl[2][64 * 72];  // [buf][key][d]

  const int tid = threadIdx.x;
  const int wid = tid >> 6, l = tid & 63, l15 = l & 15, lhi = l >> 4;
  const int qbase = blockIdx.x * 64 + wid * 16;  // x = q tile (fastest)
  const int keyb = blockIdx.y * 64;              // y = key tile
  const int b = blockIdx.z;

  const unsigned short* Qb = Qw + (size_t)b * NH * TX * HD;
  const unsigned short* Kb = Kw + (size_t)b * NH * TC * HD;

  // staging map: thread copies K rows sr, sr+32, cols sc0..sc0+7 (b128 each)
  const int sr = tid >> 3, sc0 = (tid & 7) * 8;

  bf16x8 aq0[2], aq1[2];
  f32x4 mm[2], ii[2];

  auto load_q = [&](int h, int p) {
    const unsigned short* qp =
        Qb + ((size_t)h * TX + qbase + l15) * HD + lhi * 8;
    aq0[p] = *(const bf16x8*)qp;
    aq1[p] = *(const bf16x8*)(qp + 32);
    mm[p] = *(const f32x4*)(m_ws + (size_t)(b * NH + h) * TX + qbase + 4 * lhi);
    ii[p] = *(const f32x4*)(il_ws + (size_t)(b * NH + h) * TX + qbase + 4 * lhi);
  };

  // prologue: head 0 K tile -> regs -> LDS[0]; head-0 Q state
  bf16x8 kr0 = *(const bf16x8*)(Kb + ((size_t)keyb + sr) * HD + sc0);
  bf16x8 kr1 = *(const bf16x8*)(Kb + ((size_t)keyb + sr + 32) * HD + sc0);
  load_q(0, 0);
  *(bf16x8*)&ktl[0][sr * 72 + sc0] = kr0;
  *(bf16x8*)&ktl[0][(sr + 32) * 72 + sc0] = kr1;
  __syncthreads();

  f32x4 am[4];
#pragma unroll
  for (int kb = 0; kb < 4; kb++) am[kb] = zero4();

#pragma unroll
  for (int h = 0; h < NH; h++) {
    const int cur = h & 1;

    // 1. prefetch head h+1 (K to regs, Q/m/il to the other state)
    if (h + 1 < NH) {
      kr0 = *(const bf16x8*)(Kb + ((size_t)(h + 1) * TC + keyb + sr) * HD + sc0);
      kr1 = *(const bf16x8*)(Kb + ((size_t)(h + 1) * TC + keyb + sr + 32) * HD + sc0);
      load_q(h + 1, cur ^ 1);
    }

    // 2. QK^T from LDS K tile + exp-accumulate (Q pre-scaled by 1/8)
#pragma unroll
    for (int kb = 0; kb < 4; kb++) {
      bf16x8 bk0 = *(const bf16x8*)&ktl[cur][(kb * 16 + l15) * 72 + lhi * 8];
      bf16x8 bk1 = *(const bf16x8*)&ktl[cur][(kb * 16 + l15) * 72 + 32 + lhi * 8];
      f32x4 a = zero4();
      a = mfma16(aq0[cur], bk0, a);
      a = mfma16(aq1[cur], bk1, a);
#pragma unroll
      for (int r = 0; r < 4; r++)
        am[kb][r] += __expf(a[r] - mm[cur][r]) * ii[cur][r];
    }

    // 3. commit K prefetch (anchors the loads; ~1 head-iter old by now)
    if (h + 1 < NH) {
      const int nxt = cur ^ 1;
      *(bf16x8*)&ktl[nxt][sr * 72 + sc0] = kr0;
      *(bf16x8*)&ktl[nxt][(sr + 32) * 72 + sc0] = kr1;
    }
    __syncthreads();
  }

#pragma unroll
  for (int kb = 0; kb < 4; kb++)
#pragma unroll
    for (int r = 0; r < 4; r++) {
      int trow = qbase + 4 * lhi + r;
      attm[(size_t)(b * TX + trow) * TC + keyb + kb * 16 + l15] = am[kb][r] * 0.125f;
    }
}

// ---------------------------------------------------------------------------
extern "C" void kernel_launch(void* const* d_in, const int* in_sizes, int n_in,
                              void* d_out, int out_size, void* d_ws, size_t ws_size,
                              hipStream_t stream) {
  const float* x   = (const float*)d_in[0];
  const float* ctx = (const float*)d_in[1];
  const float* Wq  = (const float*)d_in[2];
  const float* bq  = (const float*)d_in[3];
  const float* Wk  = (const float*)d_in[4];
  const float* bk  = (const float*)d_in[5];
  const float* Wv  = (const float*)d_in[6];
  const float* bv  = (const float*)d_in[7];
  const float* Wo  = (const float*)d_in[8];
  const float* bo  = (const float*)d_in[9];

  float* y_out = (float*)d_out;                       // (B, Tx, C)
  float* attm  = y_out + (size_t)Bb * TX * CC;        // (B, Tx, Tc)

  // workspace layout (16B-aligned), ~53 MB total:
  unsigned short* q_ws = (unsigned short*)d_ws;                  // B*NH*TX*HD bf16
  unsigned short* k_ws = q_ws + (size_t)Bb * NH * TX * HD;       // B*NH*TC*HD bf16
  unsigned short* v_ws = k_ws + (size_t)Bb * NH * TC * HD;       // B*NH*TC*HD bf16 (V^T)
  float* m_ws  = (float*)(v_ws + (size_t)Bb * NH * TC * HD);     // B*NH*TX f32
  float* il_ws = m_ws + (size_t)Bb * NH * TX;                    // B*NH*TX f32
  unsigned short* y_pre = (unsigned short*)(il_ws + (size_t)Bb * NH * TX);  // B*TX*CC bf16
  unsigned short* wb = y_pre + (size_t)Bb * TX * CC;             // 4x CC*CC bf16
  unsigned short* wbq = wb, *wbk = wb + CC * CC, *wbv = wb + 2 * CC * CC,
                 *wbo = wb + 3 * CC * CC;

  // bf16 input overlays (consumed before their regions are overwritten):
  unsigned short* xb = k_ws;              // read by Q-GEMM, then K-GEMM overwrites
  unsigned short* cb = (unsigned short*)attm;  // read by K/V-GEMMs, att_mean_k overwrites

  const int NX8 = Bb * TX * CC / 8, NC8 = Bb * TC * CC / 8, NW8 = CC * CC / 8;
  cvt_bf16<<<dim3(2048), 256, 0, stream>>>(x, xb, NX8);
  cvt_bf16<<<dim3(2048), 256, 0, stream>>>(ctx, cb, NC8);
  cvt_bf16<<<dim3(128), 256, 0, stream>>>(Wq, wbq, NW8);
  cvt_bf16<<<dim3(128), 256, 0, stream>>>(Wk, wbk, NW8);
  cvt_bf16<<<dim3(128), 256, 0, stream>>>(Wv, wbv, NW8);
  cvt_bf16<<<dim3(128), 256, 0, stream>>>(Wo, wbo, NW8);

  proj_gemm<0><<<dim3(CC / 64, (Bb * TX) / 64), 256, 0, stream>>>(xb, wbq, bq, q_ws, 10, 0.125f);
  proj_gemm<0><<<dim3(CC / 64, (Bb * TC) / 64), 256, 0, stream>>>(cb, wbk, bk, k_ws, 11, 1.0f);
  proj_gemm<2><<<dim3(CC / 64, (Bb * TC) / 64), 256, 0, stream>>>(cb, wbv, bv, v_ws, 11, 1.0f);
  attn_fwd<<<dim3(TX / 64, NH, Bb), 256, 0, stream>>>(q_ws, k_ws, v_ws, y_pre, m_ws, il_ws);
  att_mean_k<<<dim3(TX / 64, TC / 64, Bb), 256, 0, stream>>>(q_ws, k_ws, m_ws, il_ws, attm);
  proj_gemm<1><<<dim3(CC / 64, (Bb * TX) / 64), 256, 0, stream>>>(y_pre, wbo, bo, y_out, 10, 1.0f);
}

// Round 10
// 224.986 us; speedup vs baseline: 2.4515x; 1.1772x over previous
//
#include <hip/hip_runtime.h>

#define DEVI __device__ __forceinline__

typedef short bf16x8 __attribute__((ext_vector_type(8)));
typedef short bf16x4 __attribute__((ext_vector_type(4)));
typedef float f32x4 __attribute__((ext_vector_type(4)));

constexpr int Bb = 8, TX = 1024, TC = 2048, CC = 512, NH = 8, HD = 64;

// fp32 -> bf16 round-to-nearest-even (values here are well-behaved, no NaN/Inf)
DEVI unsigned short f2bf(float f) {
  union { float f; unsigned u; } v; v.f = f;
  return (unsigned short)((v.u + 0x7FFFu + ((v.u >> 16) & 1u)) >> 16);
}

// packed f32x2 -> bf16x2 (low = lo, high = hi); no builtin on gfx950 (T12)
DEVI unsigned cvtpk(float lo, float hi) {
  unsigned r;
  asm("v_cvt_pk_bf16_f32 %0, %1, %2" : "=v"(r) : "v"(lo), "v"(hi));
  return r;
}

DEVI f32x4 mfma16(bf16x8 a, bf16x8 b, f32x4 c) {
  return __builtin_amdgcn_mfma_f32_16x16x32_bf16(a, b, c, 0, 0, 0);
}

DEVI f32x4 zero4() { f32x4 z = {0.f, 0.f, 0.f, 0.f}; return z; }

// ---------------------------------------------------------------------------
// Bulk fp32 -> bf16 convert (grid-stride over chunks of 8).
// ---------------------------------------------------------------------------
__global__ __launch_bounds__(256) void cvt_bf16(
    const float* __restrict__ src, unsigned short* __restrict__ dst, int n8) {
  int i = blockIdx.x * 256 + threadIdx.x;
  const int stride = gridDim.x * 256;
  for (; i < n8; i += stride) {
    f32x4 a = *(const f32x4*)(src + (size_t)i * 8);
    f32x4 b = *(const f32x4*)(src + (size_t)i * 8 + 4);
    bf16x8 v;
#pragma unroll
    for (int j = 0; j < 4; j++) {
      v[j] = (short)f2bf(a[j]);
      v[j + 4] = (short)f2bf(b[j]);
    }
    *(bf16x8*)(dst + (size_t)i * 8) = v;
  }
}

// ---------------------------------------------------------------------------
// NT GEMM, all-bf16 inputs: out[r][c] = (sum_k A[r][k]*W[c][k] + bias[c])*scale
// MODE 0: out bf16 permuted to (b, h, t, d).   MODE 1: out fp32 (r*512+c).
// 64x64 tile, BK=32, 256 threads = 4 waves in 2x2, each wave 32x32 (2x2 frags).
// ---------------------------------------------------------------------------
template <int MODE>
__global__ __launch_bounds__(256) void proj_gemm(
    const unsigned short* __restrict__ A, const unsigned short* __restrict__ W,
    const float* __restrict__ bias, void* __restrict__ outp, int tlog2, float scale) {
  __shared__ __align__(16) unsigned short As[64 * 40];
  __shared__ __align__(16) unsigned short Bs[64 * 40];

  const int tid = threadIdx.x;
  const int wid = tid >> 6, l = tid & 63, l15 = l & 15, lhi = l >> 4;
  const int wm = wid >> 1, wn = wid & 1;
  const int mbase = blockIdx.y * 64, nbase = blockIdx.x * 64;
  const int sr = tid >> 2, sc0 = (tid & 3) * 8;

  f32x4 acc[2][2];
#pragma unroll
  for (int i = 0; i < 2; i++)
#pragma unroll
    for (int j = 0; j < 2; j++) acc[i][j] = zero4();

  for (int k0 = 0; k0 < CC; k0 += 32) {
    *(bf16x8*)&As[sr * 40 + sc0] =
        *(const bf16x8*)(A + (size_t)(mbase + sr) * CC + k0 + sc0);
    *(bf16x8*)&Bs[sr * 40 + sc0] =
        *(const bf16x8*)(W + (size_t)(nbase + sr) * CC + k0 + sc0);
    __syncthreads();

    bf16x8 a0 = *(const bf16x8*)&As[(wm * 32 + l15) * 40 + lhi * 8];
    bf16x8 a1 = *(const bf16x8*)&As[(wm * 32 + 16 + l15) * 40 + lhi * 8];
    bf16x8 b0 = *(const bf16x8*)&Bs[(wn * 32 + l15) * 40 + lhi * 8];
    bf16x8 b1 = *(const bf16x8*)&Bs[(wn * 32 + 16 + l15) * 40 + lhi * 8];
    acc[0][0] = mfma16(a0, b0, acc[0][0]);
    acc[0][1] = mfma16(a0, b1, acc[0][1]);
    acc[1][0] = mfma16(a1, b0, acc[1][0]);
    acc[1][1] = mfma16(a1, b1, acc[1][1]);
    __syncthreads();
  }

#pragma unroll
  for (int mi = 0; mi < 2; mi++)
#pragma unroll
    for (int ni = 0; ni < 2; ni++)
#pragma unroll
      for (int r = 0; r < 4; r++) {
        int grow = mbase + wm * 32 + mi * 16 + 4 * lhi + r;
        int gcol = nbase + wn * 32 + ni * 16 + l15;
        float val = (acc[mi][ni][r] + bias[gcol]) * scale;
        if (MODE == 0) {
          int T = 1 << tlog2;
          int bq = grow >> tlog2, tt = grow & (T - 1);
          int h = gcol >> 6, d = gcol & 63;
          size_t oidx = ((size_t)(bq * NH + h) * T + tt) * HD + d;
          ((unsigned short*)outp)[oidx] = f2bf(val);
        } else {
          ((float*)outp)[(size_t)grow * CC + gcol] = val;
        }
      }
}

// ---------------------------------------------------------------------------
// Fused K+V projection GEMM: one A (ctx) tile staged once feeds both Wk and
// Wv B-tiles (A global traffic halved, 8 MFMA per staging round instead of 4).
// K epilogue -> (b,h,t,d) bf16; V epilogue -> V^T (b,h,d,t) bf16.
// ---------------------------------------------------------------------------
__global__ __launch_bounds__(256) void kv_gemm(
    const unsigned short* __restrict__ A, const unsigned short* __restrict__ Wk,
    const unsigned short* __restrict__ Wv, const float* __restrict__ bk,
    const float* __restrict__ bv, unsigned short* __restrict__ k_out,
    unsigned short* __restrict__ v_out) {
  __shared__ __align__(16) unsigned short As[64 * 40];
  __shared__ __align__(16) unsigned short Bks[64 * 40];
  __shared__ __align__(16) unsigned short Bvs[64 * 40];

  const int tid = threadIdx.x;
  const int wid = tid >> 6, l = tid & 63, l15 = l & 15, lhi = l >> 4;
  const int wm = wid >> 1, wn = wid & 1;
  const int mbase = blockIdx.y * 64, nbase = blockIdx.x * 64;
  const int sr = tid >> 2, sc0 = (tid & 3) * 8;

  f32x4 acck[2][2], accv[2][2];
#pragma unroll
  for (int i = 0; i < 2; i++)
#pragma unroll
    for (int j = 0; j < 2; j++) { acck[i][j] = zero4(); accv[i][j] = zero4(); }

  for (int k0 = 0; k0 < CC; k0 += 32) {
    *(bf16x8*)&As[sr * 40 + sc0] =
        *(const bf16x8*)(A + (size_t)(mbase + sr) * CC + k0 + sc0);
    *(bf16x8*)&Bks[sr * 40 + sc0] =
        *(const bf16x8*)(Wk + (size_t)(nbase + sr) * CC + k0 + sc0);
    *(bf16x8*)&Bvs[sr * 40 + sc0] =
        *(const bf16x8*)(Wv + (size_t)(nbase + sr) * CC + k0 + sc0);
    __syncthreads();

    bf16x8 a0 = *(const bf16x8*)&As[(wm * 32 + l15) * 40 + lhi * 8];
    bf16x8 a1 = *(const bf16x8*)&As[(wm * 32 + 16 + l15) * 40 + lhi * 8];
    bf16x8 k0f = *(const bf16x8*)&Bks[(wn * 32 + l15) * 40 + lhi * 8];
    bf16x8 k1f = *(const bf16x8*)&Bks[(wn * 32 + 16 + l15) * 40 + lhi * 8];
    bf16x8 v0f = *(const bf16x8*)&Bvs[(wn * 32 + l15) * 40 + lhi * 8];
    bf16x8 v1f = *(const bf16x8*)&Bvs[(wn * 32 + 16 + l15) * 40 + lhi * 8];
    acck[0][0] = mfma16(a0, k0f, acck[0][0]);
    acck[0][1] = mfma16(a0, k1f, acck[0][1]);
    acck[1][0] = mfma16(a1, k0f, acck[1][0]);
    acck[1][1] = mfma16(a1, k1f, acck[1][1]);
    accv[0][0] = mfma16(a0, v0f, accv[0][0]);
    accv[0][1] = mfma16(a0, v1f, accv[0][1]);
    accv[1][0] = mfma16(a1, v0f, accv[1][0]);
    accv[1][1] = mfma16(a1, v1f, accv[1][1]);
    __syncthreads();
  }

#pragma unroll
  for (int mi = 0; mi < 2; mi++)
#pragma unroll
    for (int ni = 0; ni < 2; ni++)
#pragma unroll
      for (int r = 0; r < 4; r++) {
        int grow = mbase + wm * 32 + mi * 16 + 4 * lhi + r;
        int gcol = nbase + wn * 32 + ni * 16 + l15;
        int bq = grow >> 11, tt = grow & (TC - 1);
        int h = gcol >> 6, d = gcol & 63;
        float kv = acck[mi][ni][r] + bk[gcol];
        float vv = accv[mi][ni][r] + bv[gcol];
        k_out[((size_t)(bq * NH + h) * TC + tt) * HD + d] = f2bf(kv);
        v_out[((size_t)(bq * NH + h) * HD + d) * TC + tt] = f2bf(vv);
      }
}

// ---------------------------------------------------------------------------
// Flash attention fwd v6 — 8 waves / 512 threads per block (128 q-rows), each
// wave a 16-row q-tile of the same (b,h); K/V LDS staging amortized over 2x
// the waves (16 waves/CU) and K/V refetch per (b,h) halved. Per-wave math
// identical to v5: swapped-QK^T in-register softmax, cvt_pk+shfl P
// redistribution, swapped PV, defer-max. One barrier per iteration; prefetch
// issued top-of-iter, LDS-committed at the end (the commit anchors the loads).
// ---------------------------------------------------------------------------
__global__ __launch_bounds__(512) void attn_fwd(
    const unsigned short* __restrict__ Qw, const unsigned short* __restrict__ Kw,
    const unsigned short* __restrict__ Vtw, unsigned short* __restrict__ y_pre,
    float* __restrict__ m_ws, float* __restrict__ il_ws) {
  __shared__ __align__(16) unsigned short ktl[2][64 * 72];  // [buf][key][d]
  __shared__ __align__(16) unsigned short vtl[2][64 * 72];  // [buf][d][key]

  const int tid = threadIdx.x;
  const int wid = tid >> 6, l = tid & 63, l15 = l & 15, lhi = l >> 4;
  const int qg = blockIdx.x, h = blockIdx.y, b = blockIdx.z;
  const int qbase = qg * 128 + wid * 16;

  const unsigned short* Qh = Qw + (size_t)(b * NH + h) * TX * HD;
  const unsigned short* Kh = Kw + (size_t)(b * NH + h) * TC * HD;
  const unsigned short* Vt = Vtw + (size_t)(b * NH + h) * TC * HD;  // (d, t)

  bf16x8 aq0 = *(const bf16x8*)(Qh + (size_t)(qbase + l15) * HD + lhi * 8);
  bf16x8 aq1 = *(const bf16x8*)(Qh + (size_t)(qbase + l15) * HD + 32 + lhi * 8);

  f32x4 accy[4];
#pragma unroll
  for (int db = 0; db < 4; db++) accy[db] = zero4();
  float mrun = -1e30f, lrun = 0.f;

  // P-redistribution lane map: word j of k-octet 8*lhi <- lane
  // l15 + 32*(lhi&1) + 16*(j>=2), pk word (j&1), kb block (lhi>>1) (+2 hi).
  const int sl0 = l15 + ((lhi & 1) << 5);
  const int sl1 = sl0 + 16;
  const bool sel = ((lhi >> 1) & 1) != 0;

  // staging map (512 threads): thread copies ONE b128 of K and of V^T:
  // row sr = tid>>3 (0..63), cols sc0..sc0+7
  const int sr = tid >> 3, sc0 = (tid & 7) * 8;

  // prologue: tile 0 -> regs -> LDS[0]
  bf16x8 kr = *(const bf16x8*)(Kh + (size_t)sr * HD + sc0);
  bf16x8 vp = *(const bf16x8*)(Vt + (size_t)sr * TC + sc0);
  *(bf16x8*)&ktl[0][sr * 72 + sc0] = kr;
  *(bf16x8*)&vtl[0][sr * 72 + sc0] = vp;
  __syncthreads();

  constexpr int NT = TC / 64;
  for (int kt = 0; kt < NT; kt++) {
    const int cur = kt & 1;

    // 1. issue prefetch for tile kt+1 (oldest ops of the iteration)
    if (kt + 1 < NT) {
      const int keyn = (kt + 1) * 64;
      kr = *(const bf16x8*)(Kh + (size_t)(keyn + sr) * HD + sc0);
      vp = *(const bf16x8*)(Vt + (size_t)sr * TC + keyn + sc0);
    }

    // 2. swapped QK^T: s[kb][r] = S[key=16kb+4lhi+r][q=l15]
    f32x4 s[4];
#pragma unroll
    for (int kb = 0; kb < 4; kb++) {
      bf16x8 bk0 = *(const bf16x8*)&ktl[cur][(kb * 16 + l15) * 72 + lhi * 8];
      bf16x8 bk1 = *(const bf16x8*)&ktl[cur][(kb * 16 + l15) * 72 + 32 + lhi * 8];
      f32x4 a = zero4();
      a = mfma16(bk0, aq0, a);
      a = mfma16(bk1, aq1, a);
      s[kb] = a;
    }

    // 3. per-lane softmax (this lane's q-row): in-lane max + 2 shuffles
    float mx = s[0][0];
#pragma unroll
    for (int kb = 0; kb < 4; kb++)
#pragma unroll
      for (int r = 0; r < 4; r++) mx = fmaxf(mx, s[kb][r]);
    mx = fmaxf(mx, __shfl_xor(mx, 16));
    mx = fmaxf(mx, __shfl_xor(mx, 32));

    // defer-max: rescale only when the e^5 bound would be exceeded
    if (__any(mx - mrun > 5.0f)) {
      float mn = fmaxf(mrun, mx);
      float sc = __expf(mrun - mn);
      lrun *= sc;
      mrun = mn;
#pragma unroll
      for (int db = 0; db < 4; db++)
#pragma unroll
        for (int r = 0; r < 4; r++) accy[db][r] *= sc;
    }

    // 4. p = exp(s - m); row sum in-lane + 2 shuffles
    float p[4][4];
    float ps = 0.f;
#pragma unroll
    for (int kb = 0; kb < 4; kb++)
#pragma unroll
      for (int r = 0; r < 4; r++) {
        p[kb][r] = __expf(s[kb][r] - mrun);
        ps += p[kb][r];
      }
    ps += __shfl_xor(ps, 16);
    ps += __shfl_xor(ps, 32);
    lrun += ps;

    // 5. pack P to bf16 pairs and redistribute into the PV B-fragment
    unsigned pkw[4][2];
#pragma unroll
    for (int kb = 0; kb < 4; kb++) {
      pkw[kb][0] = cvtpk(p[kb][0], p[kb][1]);
      pkw[kb][1] = cvtpk(p[kb][2], p[kb][3]);
    }
    unsigned a00 = (unsigned)__shfl((int)pkw[0][0], sl0);
    unsigned a01 = (unsigned)__shfl((int)pkw[0][1], sl0);
    unsigned a10 = (unsigned)__shfl((int)pkw[1][0], sl0);
    unsigned a11 = (unsigned)__shfl((int)pkw[1][1], sl0);
    unsigned c00 = (unsigned)__shfl((int)pkw[0][0], sl1);
    unsigned c01 = (unsigned)__shfl((int)pkw[0][1], sl1);
    unsigned c10 = (unsigned)__shfl((int)pkw[1][0], sl1);
    unsigned c11 = (unsigned)__shfl((int)pkw[1][1], sl1);
    unsigned e00 = (unsigned)__shfl((int)pkw[2][0], sl0);
    unsigned e01 = (unsigned)__shfl((int)pkw[2][1], sl0);
    unsigned e10 = (unsigned)__shfl((int)pkw[3][0], sl0);
    unsigned e11 = (unsigned)__shfl((int)pkw[3][1], sl0);
    unsigned g00 = (unsigned)__shfl((int)pkw[2][0], sl1);
    unsigned g01 = (unsigned)__shfl((int)pkw[2][1], sl1);
    unsigned g10 = (unsigned)__shfl((int)pkw[3][0], sl1);
    unsigned g11 = (unsigned)__shfl((int)pkw[3][1], sl1);
    union { unsigned u[4]; bf16x8 v; } B0, B1;
    B0.u[0] = sel ? a10 : a00;
    B0.u[1] = sel ? a11 : a01;
    B0.u[2] = sel ? c10 : c00;
    B0.u[3] = sel ? c11 : c01;
    B1.u[0] = sel ? e10 : e00;
    B1.u[1] = sel ? e11 : e01;
    B1.u[2] = sel ? g10 : g00;
    B1.u[3] = sel ? g11 : g01;

    // 6. PV swapped: accy[db][r] = y[q=l15][d=16db+4lhi+r]
#pragma unroll
    for (int db = 0; db < 4; db++) {
      bf16x8 bv0 = *(const bf16x8*)&vtl[cur][(db * 16 + l15) * 72 + lhi * 8];
      bf16x8 bv1 = *(const bf16x8*)&vtl[cur][(db * 16 + l15) * 72 + 32 + lhi * 8];
      accy[db] = mfma16(bv0, B0.v, accy[db]);
      accy[db] = mfma16(bv1, B1.v, accy[db]);
    }

    // 7. commit prefetch to the other buffer (loads are ~1 iteration old)
    if (kt + 1 < NT) {
      const int nxt = cur ^ 1;
      *(bf16x8*)&ktl[nxt][sr * 72 + sc0] = kr;
      *(bf16x8*)&vtl[nxt][sr * 72 + sc0] = vp;
    }
    __syncthreads();
  }

  const float il = 1.f / lrun;

#pragma unroll
  for (int db = 0; db < 4; db++) {
    bf16x4 o;
#pragma unroll
    for (int r = 0; r < 4; r++) o[r] = (short)f2bf(accy[db][r] * il);
    *(bf16x4*)(y_pre + (size_t)(b * TX + qbase + l15) * CC + h * HD + db * 16 +
               4 * lhi) = o;
  }
  if (lhi == 0) {
    int idx = (b * NH + h) * TX + qbase + l15;
    m_ws[idx] = mrun;
    il_ws[idx] = il;
  }
}

// ---------------------------------------------------------------------------
// att_mean v4: attn_fwd-style pipeline. Block = 4 waves sharing one
// (b, 64-q-tile, 64-key-tile); loop over the 8 heads with the K tile staged
// in LDS (double-buffered, prefetch at top / commit at bottom, one barrier
// per head). Q/m/il double-buffered in regs; consecutive blocks (x = q)
// stage the identical K tile -> L2-hot.
// ---------------------------------------------------------------------------
__global__ __launch_bounds__(256) void att_mean_k(
    const unsigned short* __restrict__ Qw, const unsigned short* __restrict__ Kw,
    const float* __restrict__ m_ws, const float* __restrict__ il_ws,
    float* __restrict__ attm) {
  __shared__ __align__(16) unsigned short ktl[2][64 * 72];  // [buf][key][d]

  const int tid = threadIdx.x;
  const int wid = tid >> 6, l = tid & 63, l15 = l & 15, lhi = l >> 4;
  const int qbase = blockIdx.x * 64 + wid * 16;  // x = q tile (fastest)
  const int keyb = blockIdx.y * 64;              // y = key tile
  const int b = blockIdx.z;

  const unsigned short* Qb = Qw + (size_t)b * NH * TX * HD;
  const unsigned short* Kb = Kw + (size_t)b * NH * TC * HD;

  const int sr = tid >> 3, sc0 = (tid & 7) * 8;

  bf16x8 aq0[2], aq1[2];
  f32x4 mm[2], ii[2];

  auto load_q = [&](int h, int p) {
    const unsigned short* qp =
        Qb + ((size_t)h * TX + qbase + l15) * HD + lhi * 8;
    aq0[p] = *(const bf16x8*)qp;
    aq1[p] = *(const bf16x8*)(qp + 32);
    mm[p] = *(const f32x4*)(m_ws + (size_t)(b * NH + h) * TX + qbase + 4 * lhi);
    ii[p] = *(const f32x4*)(il_ws + (size_t)(b * NH + h) * TX + qbase + 4 * lhi);
  };

  bf16x8 kr0 = *(const bf16x8*)(Kb + ((size_t)keyb + sr) * HD + sc0);
  bf16x8 kr1 = *(const bf16x8*)(Kb + ((size_t)keyb + sr + 32) * HD + sc0);
  load_q(0, 0);
  *(bf16x8*)&ktl[0][sr * 72 + sc0] = kr0;
  *(bf16x8*)&ktl[0][(sr + 32) * 72 + sc0] = kr1;
  __syncthreads();

  f32x4 am[4];
#pragma unroll
  for (int kb = 0; kb < 4; kb++) am[kb] = zero4();

#pragma unroll
  for (int h = 0; h < NH; h++) {
    const int cur = h & 1;

    if (h + 1 < NH) {
      kr0 = *(const bf16x8*)(Kb + ((size_t)(h + 1) * TC + keyb + sr) * HD + sc0);
      kr1 = *(const bf16x8*)(Kb + ((size_t)(h + 1) * TC + keyb + sr + 32) * HD + sc0);
      load_q(h + 1, cur ^ 1);
    }

#pragma unroll
    for (int kb = 0; kb < 4; kb++) {
      bf16x8 bk0 = *(const bf16x8*)&ktl[cur][(kb * 16 + l15) * 72 + lhi * 8];
      bf16x8 bk1 = *(const bf16x8*)&ktl[cur][(kb * 16 + l15) * 72 + 32 + lhi * 8];
      f32x4 a = zero4();
      a = mfma16(aq0[cur], bk0, a);
      a = mfma16(aq1[cur], bk1, a);
#pragma unroll
      for (int r = 0; r < 4; r++)
        am[kb][r] += __expf(a[r] - mm[cur][r]) * ii[cur][r];
    }

    if (h + 1 < NH) {
      const int nxt = cur ^ 1;
      *(bf16x8*)&ktl[nxt][sr * 72 + sc0] = kr0;
      *(bf16x8*)&ktl[nxt][(sr + 32) * 72 + sc0] = kr1;
    }
    __syncthreads();
  }

#pragma unroll
  for (int kb = 0; kb < 4; kb++)
#pragma unroll
    for (int r = 0; r < 4; r++) {
      int trow = qbase + 4 * lhi + r;
      attm[(size_t)(b * TX + trow) * TC + keyb + kb * 16 + l15] = am[kb][r] * 0.125f;
    }
}

// ---------------------------------------------------------------------------
extern "C" void kernel_launch(void* const* d_in, const int* in_sizes, int n_in,
                              void* d_out, int out_size, void* d_ws, size_t ws_size,
                              hipStream_t stream) {
  const float* x   = (const float*)d_in[0];
  const float* ctx = (const float*)d_in[1];
  const float* Wq  = (const float*)d_in[2];
  const float* bq  = (const float*)d_in[3];
  const float* Wk  = (const float*)d_in[4];
  const float* bk  = (const float*)d_in[5];
  const float* Wv  = (const float*)d_in[6];
  const float* bv  = (const float*)d_in[7];
  const float* Wo  = (const float*)d_in[8];
  const float* bo  = (const float*)d_in[9];

  float* y_out = (float*)d_out;                       // (B, Tx, C)
  float* attm  = y_out + (size_t)Bb * TX * CC;        // (B, Tx, Tc)

  // workspace layout (16B-aligned), ~53 MB total:
  unsigned short* q_ws = (unsigned short*)d_ws;                  // B*NH*TX*HD bf16
  unsigned short* k_ws = q_ws + (size_t)Bb * NH * TX * HD;       // B*NH*TC*HD bf16
  unsigned short* v_ws = k_ws + (size_t)Bb * NH * TC * HD;       // B*NH*TC*HD bf16 (V^T)
  float* m_ws  = (float*)(v_ws + (size_t)Bb * NH * TC * HD);     // B*NH*TX f32
  float* il_ws = m_ws + (size_t)Bb * NH * TX;                    // B*NH*TX f32
  unsigned short* y_pre = (unsigned short*)(il_ws + (size_t)Bb * NH * TX);  // B*TX*CC bf16
  unsigned short* wb = y_pre + (size_t)Bb * TX * CC;             // 4x CC*CC bf16
  unsigned short* wbq = wb, *wbk = wb + CC * CC, *wbv = wb + 2 * CC * CC,
                 *wbo = wb + 3 * CC * CC;

  // bf16 input overlays (consumed before their regions are overwritten):
  unsigned short* xb = k_ws;              // read by Q-GEMM, then kv_gemm overwrites
  unsigned short* cb = (unsigned short*)attm;  // read by kv_gemm, att_mean_k overwrites

  const int NX8 = Bb * TX * CC / 8, NC8 = Bb * TC * CC / 8, NW8 = CC * CC / 8;
  cvt_bf16<<<dim3(2048), 256, 0, stream>>>(x, xb, NX8);
  cvt_bf16<<<dim3(2048), 256, 0, stream>>>(ctx, cb, NC8);
  cvt_bf16<<<dim3(128), 256, 0, stream>>>(Wq, wbq, NW8);
  cvt_bf16<<<dim3(128), 256, 0, stream>>>(Wk, wbk, NW8);
  cvt_bf16<<<dim3(128), 256, 0, stream>>>(Wv, wbv, NW8);
  cvt_bf16<<<dim3(128), 256, 0, stream>>>(Wo, wbo, NW8);

  proj_gemm<0><<<dim3(CC / 64, (Bb * TX) / 64), 256, 0, stream>>>(xb, wbq, bq, q_ws, 10, 0.125f);
  kv_gemm<<<dim3(CC / 64, (Bb * TC) / 64), 256, 0, stream>>>(cb, wbk, wbv, bk, bv, k_ws, v_ws);
  attn_fwd<<<dim3(TX / 128, NH, Bb), 512, 0, stream>>>(q_ws, k_ws, v_ws, y_pre, m_ws, il_ws);
  att_mean_k<<<dim3(TX / 64, TC / 64, Bb), 256, 0, stream>>>(q_ws, k_ws, m_ws, il_ws, attm);
  proj_gemm<1><<<dim3(CC / 64, (Bb * TX) / 64), 256, 0, stream>>>(y_pre, wbo, bo, y_out, 10, 1.0f);
}